// Round 6
// baseline (917.884 us; speedup 1.0000x reference)
//
#include <hip/hip_runtime.h>
#include <math.h>

// ---------------------------------------------------------------------------
// RecurrentNatureCNN: conv1(8x8,s4) -> conv2(4x4,s2) -> conv3(3x3,s1) -> FC
//                     -> LSTM(T=64,B=32,H=256)
// N = T*B = 2048 images.
// R14: = R13 + forced register residency for i/f gates. R13 PMC: VGPR=64 of
//      a 128 budget -- compiler rematerialized (re-loaded) all 96 weight
//      dwords from L2 every step -> 393 KB/step/CU = the measured 6.2K
//      cyc/step L2 floor. R14 pins 64 dw (i,f gates; 16 named uint4) via
//      opaque asm so the allocator must keep them live (64+~40 < 128, no
//      spill headroom risk); g streams from L2 via laundered (non-hoistable)
//      address; o stays in LDS. Streamed traffic 393 -> 131 KB/step/CU.
//      conv/GEMM stages unchanged from R8.
// ---------------------------------------------------------------------------

#define NIMG 2048

typedef _Float16 half2_t __attribute__((ext_vector_type(2)));
typedef __fp16 fp16x2_t __attribute__((ext_vector_type(2)));

__device__ inline unsigned short f2h_bits(float f) {
    union { _Float16 h; unsigned short u; } x;
    x.h = (_Float16)f;
    return x.u;
}

__device__ inline unsigned pack2_rne(float a, float b) {
    return (unsigned)f2h_bits(a) | ((unsigned)f2h_bits(b) << 16);
}

__device__ inline unsigned pack2_fast(float a, float b) {
#if __has_builtin(__builtin_amdgcn_cvt_pkrtz)
    union { fp16x2_t h; unsigned u; } x;
    x.h = __builtin_amdgcn_cvt_pkrtz(a, b);
    return x.u;
#else
    return pack2_rne(a, b);
#endif
}

__device__ inline float dot2(unsigned hu, unsigned wu, float acc) {
    union { unsigned u; half2_t h; } a, b;
    a.u = hu; b.u = wu;
#if __has_builtin(__builtin_amdgcn_fdot2)
    return __builtin_amdgcn_fdot2(a.h, b.h, acc, false);
#else
    return acc + (float)a.h.x * (float)b.h.x + (float)a.h.y * (float)b.h.y;
#endif
}

__device__ inline float fast_tanh(float x) {
    return 1.0f - 2.0f / (__expf(2.0f * x) + 1.0f);
}

// ---- generic small transpose: in (R,C) -> out (C,R) -----------------------
__global__ void transpose_kernel(const float* __restrict__ in, float* __restrict__ out,
                                 int R, int C) {
    int idx = blockIdx.x * 256 + threadIdx.x;
    if (idx < R * C) {
        int r = idx / C, c = idx - r * C;
        out[c * R + r] = in[idx];
    }
}

// ---- pack whh (1024,256) fp32 -> f16x2 pairs, uint4-interleaved by row -----
// As uint4: wp4[d4*1024 + row] = row's packed k = [d4*8, d4*8+8).
__global__ void pack_whh_pairs_kernel(const float* __restrict__ whh,
                                      unsigned* __restrict__ wp) {
    int idx = blockIdx.x * 256 + threadIdx.x;  // 0..131071
    if (idx >= 131072) return;
    int d4 = idx >> 12;
    int rem = idx & 4095;
    int row = rem >> 2;
    int j = idx & 3;
    int k0 = d4 * 8 + j * 2;
    const float* src = whh + (size_t)row * 256 + k0;
    wp[idx] = pack2_rne(src[0], src[1]);
}

// ---- pack w1 (32,4,8,8) fp32 -> f16x2 pairs along kx: w1p[oc][ic][ky][kxp] -
__global__ void pack_w1_kernel(const float* __restrict__ w1, unsigned* __restrict__ w1p) {
    int idx = blockIdx.x * 256 + threadIdx.x;  // 0..4095
    if (idx >= 4096) return;
    int oc = idx >> 7, rem = idx & 127;
    int ic = rem >> 5, ky = (rem >> 2) & 7, kxp = rem & 3;
    const float* src = w1 + (((size_t)oc * 4 + ic) * 8 + ky) * 8 + kxp * 2;
    w1p[idx] = pack2_rne(src[0], src[1]);
}

// ---- pack w2 (64,32,4,4) fp32 -> f16x2 pairs: w2p[(ic*4+ky)*2+kxp][oc] -----
__global__ void pack_w2_kernel(const float* __restrict__ w2, unsigned* __restrict__ w2p) {
    int idx = blockIdx.x * 256 + threadIdx.x;  // 0..16383
    if (idx >= 16384) return;
    int p = idx >> 6, oc = idx & 63;
    int ic = p >> 3, ky = (p >> 1) & 3, kxp = p & 1;
    const float* src = w2 + (size_t)oc * 512 + ic * 16 + ky * 4 + kxp * 2;
    w2p[idx] = pack2_rne(src[0], src[1]);
}

// ---- conv1: x (n,4,64,64)/255 -> relu -> z1 f16 (n,32,15,16 padded) --------
__global__ __launch_bounds__(1024) void conv1_kernel(const float* __restrict__ x,
                                                     const unsigned* __restrict__ w1p,
                                                     const float* __restrict__ b,
                                                     unsigned short* __restrict__ z1) {
    __shared__ unsigned short xs[4 * 64 * 64];  // f16, 32768 B
    int n = blockIdx.x;
    int tid = threadIdx.x;
    const float* xp = x + (size_t)n * 16384;
    const float inv = 1.0f / 255.0f;
    for (int i = tid * 4; i < 16384; i += 4096) {
        float4 v = *(const float4*)(xp + i);
        uint2 q;
        q.x = pack2_fast(v.x * inv, v.y * inv);
        q.y = pack2_fast(v.z * inv, v.w * inv);
        *(uint2*)&xs[i] = q;
    }
    __syncthreads();
    int lane = tid & 63, wave = tid >> 6;
    int gg = __builtin_amdgcn_readfirstlane(wave & 3);
    int pos = (wave >> 2) * 64 + lane;  // 0..255
    if (pos < 225) {
        int oy = pos / 15, ox = pos - oy * 15;
        float acc[8];
        const float* bp = b + gg * 8;
#pragma unroll
        for (int u = 0; u < 8; ++u) acc[u] = bp[u];
        for (int ic = 0; ic < 4; ++ic) {
#pragma unroll
            for (int ky = 0; ky < 8; ++ky) {
                const unsigned short* row = &xs[(ic * 64 + oy * 4 + ky) * 64 + ox * 4];
                uint2 qa = *(const uint2*)row;        // cols +0..3 (2 pairs)
                uint2 qb = *(const uint2*)(row + 4);  // cols +4..7 (2 pairs)
                const unsigned* wp = w1p + ((((gg * 8) * 4 + ic) * 8 + ky) * 4);
#pragma unroll
                for (int u = 0; u < 8; ++u) {
                    const unsigned* wu = wp + u * 128;  // (oc stride 4*8*4)
                    acc[u] = dot2(qa.x, wu[0], acc[u]);
                    acc[u] = dot2(qa.y, wu[1], acc[u]);
                    acc[u] = dot2(qb.x, wu[2], acc[u]);
                    acc[u] = dot2(qb.y, wu[3], acc[u]);
                }
            }
        }
        unsigned short* op = z1 + (size_t)n * 7680 + (gg * 8) * 240 + oy * 16 + ox;
#pragma unroll
        for (int u = 0; u < 8; ++u) op[u * 240] = f2h_bits(fmaxf(acc[u], 0.0f));
    }
}

// ---- conv2: z1 f16 (n,32,15,16) -> relu -> z2 fp32 (n,64,6,6) --------------
__global__ __launch_bounds__(768) void conv2_kernel(const unsigned short* __restrict__ z1,
                                                    const unsigned* __restrict__ w2p,
                                                    const float* __restrict__ bias,
                                                    float* __restrict__ out) {
    __shared__ unsigned short xs[2][32 * 15 * 16];  // f16, 30720 B
    int tid = threadIdx.x;
    int n0 = blockIdx.x * 2;
#pragma unroll
    for (int img = 0; img < 2; ++img) {
        const unsigned* src = (const unsigned*)(z1 + (size_t)(n0 + img) * 7680);
        unsigned* dst = (unsigned*)xs[img];
        for (int i = tid; i < 3840; i += 768) dst[i] = src[i];
    }
    __syncthreads();
    int lane = tid & 63, wave = tid >> 6;  // wave 0..11
    int img = wave / 6;
    int oy = wave - img * 6;
    int n = n0 + img;
    float bv = bias[lane];
    float* op = out + (size_t)n * 2304 + lane * 36;
    float acc[6];
#pragma unroll
    for (int u = 0; u < 6; ++u) acc[u] = bv;
    for (int ic = 0; ic < 32; ++ic) {
#pragma unroll
        for (int ky = 0; ky < 4; ++ky) {
            const unsigned short* row = &xs[img][(ic * 15 + oy * 2 + ky) * 16];
            uint4 pa = *(const uint4*)row;        // pairs 0..3  (cols 0..7)
            uint4 pb = *(const uint4*)(row + 8);  // pairs 4..7  (cols 8..15)
            unsigned p[8] = {pa.x, pa.y, pa.z, pa.w, pb.x, pb.y, pb.z, pb.w};
            const unsigned* wpp = w2p + ((ic * 4 + ky) * 2) * 64 + lane;
            unsigned wa = wpp[0];   // kx 0,1
            unsigned wb = wpp[64];  // kx 2,3
#pragma unroll
            for (int u = 0; u < 6; ++u) {
                acc[u] = dot2(p[u], wa, acc[u]);
                acc[u] = dot2(p[u + 1], wb, acc[u]);
            }
        }
    }
#pragma unroll
    for (int u = 0; u < 6; ++u) op[oy * 6 + u] = fmaxf(acc[u], 0.0f);
}

// ---- conv3: z2 (n,64,6,6) -> relu -> (n,64,4,4)  (fp32, unchanged) ---------
__global__ __launch_bounds__(512) void conv3_kernel(const float* __restrict__ x,
                                                    const float* __restrict__ wt,
                                                    const float* __restrict__ bias,
                                                    float* __restrict__ out) {
    __shared__ float xs[4][64 * 6 * 8];  // 49152 B
    int tid = threadIdx.x;
    int n0 = blockIdx.x * 4;
    for (int img = 0; img < 4; ++img) {
        const float* src = x + (size_t)(n0 + img) * 2304;
        for (int s = tid; s < 2304; s += 512) {
            int ic = s / 36;
            int rem = s - ic * 36;
            int r = rem / 6;
            int c = rem - r * 6;
            xs[img][(ic * 6 + r) * 8 + c] = src[s];
        }
    }
    __syncthreads();
    int lane = tid & 63, wave = tid >> 6;  // 0..7
    int img = wave >> 1;
    int half = wave & 1;
    int n = n0 + img;
    float bv = bias[lane];
    float* op = out + (size_t)n * 1024 + lane * 16;
    for (int q = 0; q < 2; ++q) {
        int oy = half * 2 + q;
        float acc[4];
#pragma unroll
        for (int u = 0; u < 4; ++u) acc[u] = bv;
        for (int ic = 0; ic < 64; ++ic) {
#pragma unroll
            for (int ky = 0; ky < 3; ++ky) {
                const float* xrow = &xs[img][(ic * 6 + oy + ky) * 8];
                float xr[8];
                *(float4*)&xr[0] = *(const float4*)&xrow[0];
                *(float4*)&xr[4] = *(const float4*)&xrow[4];
                const float* wp = wt + ((ic * 3 + ky) * 3) * 64 + lane;
#pragma unroll
                for (int kx = 0; kx < 3; ++kx) {
                    float wv = wp[kx * 64];
#pragma unroll
                    for (int u = 0; u < 4; ++u) acc[u] += xr[u + kx] * wv;
                }
            }
        }
#pragma unroll
        for (int u = 0; u < 4; ++u) op[oy * 4 + u] = fmaxf(acc[u], 0.0f);
    }
}

// ---- GEMM: C(M,N) = [relu]( A(M,K) @ B(N,K)^T + bias [+ bias2] ) -----------
__global__ __launch_bounds__(256) void gemm_bt(const float* __restrict__ A,
                                               const float* __restrict__ B,
                                               const float* __restrict__ bias,
                                               const float* __restrict__ bias2,
                                               float* __restrict__ C,
                                               int M, int N, int K, int relu) {
    __shared__ float As[16][68];
    __shared__ float Bs[16][68];
    int tid = threadIdx.x;
    int m0 = blockIdx.y * 64, n0 = blockIdx.x * 64;
    int tx = tid & 15, ty = tid >> 4;
    int lr = tid >> 2;
    int lk = (tid & 3) * 4;
    const float* Ap = A + (size_t)(m0 + lr) * K + lk;
    const float* Bp = B + (size_t)(n0 + lr) * K + lk;
    float acc[4][4];
#pragma unroll
    for (int i = 0; i < 4; ++i)
#pragma unroll
        for (int j = 0; j < 4; ++j) acc[i][j] = 0.0f;

    for (int k0 = 0; k0 < K; k0 += 16) {
        float4 av = *(const float4*)(Ap + k0);
        float4 bv = *(const float4*)(Bp + k0);
        __syncthreads();
        As[lk + 0][lr] = av.x;
        As[lk + 1][lr] = av.y;
        As[lk + 2][lr] = av.z;
        As[lk + 3][lr] = av.w;
        Bs[lk + 0][lr] = bv.x;
        Bs[lk + 1][lr] = bv.y;
        Bs[lk + 2][lr] = bv.z;
        Bs[lk + 3][lr] = bv.w;
        __syncthreads();
#pragma unroll
        for (int kk = 0; kk < 16; ++kk) {
            float a[4], b[4];
            *(float4*)a = *(const float4*)&As[kk][ty * 4];
            *(float4*)b = *(const float4*)&Bs[kk][tx * 4];
#pragma unroll
            for (int i = 0; i < 4; ++i)
#pragma unroll
                for (int j = 0; j < 4; ++j) acc[i][j] += a[i] * b[j];
        }
    }
    float bb[4];
#pragma unroll
    for (int j = 0; j < 4; ++j) {
        float v = bias[n0 + tx * 4 + j];
        if (bias2) v += bias2[n0 + tx * 4 + j];
        bb[j] = v;
    }
#pragma unroll
    for (int i = 0; i < 4; ++i) {
        float4 o;
        o.x = acc[i][0] + bb[0];
        o.y = acc[i][1] + bb[1];
        o.z = acc[i][2] + bb[2];
        o.w = acc[i][3] + bb[3];
        if (relu) {
            o.x = fmaxf(o.x, 0.0f);
            o.y = fmaxf(o.y, 0.0f);
            o.z = fmaxf(o.z, 0.0f);
            o.w = fmaxf(o.w, 0.0f);
        }
        *(float4*)&C[(size_t)(m0 + ty * 4 + i) * N + n0 + tx * 4] = o;
    }
}

// ---- LSTM R14: 32 blocks (one per env), 1024 threads ----------------------
// Thread (u = tt&255, q = tt>>8) owns k-quarter q of gate rows:
//   regs (PINNED via opaque asm -- compiler cannot rematerialize):
//        i-row u, f-row 256+u k-octets q8..q8+7 -> 16 named uint4 = 64 dw
//   L2-streamed per step (laundered addr, non-hoistable): g-row 512+u = 8 uint4
//   LDS: o-row u k-quarter (from wo, 128 KB, conflict-free b128)
// Partials reduced over q via 16 KB LDS exchange; q==0 waves do the c/h
// update + h broadcast. Streamed L2 traffic: 131 KB/step/CU (was 393).
__global__ __launch_bounds__(1024) void lstm_kernel(const float* __restrict__ gi,
                                                    const unsigned* __restrict__ wp,
                                                    const int* __restrict__ done,
                                                    const float* __restrict__ h0,
                                                    const float* __restrict__ c0,
                                                    float* __restrict__ out) {
    __shared__ alignas(16) unsigned wo[32768];  // o-rows f16x2: [d4][256][4], 128 KB
    __shared__ alignas(16) unsigned h2u[128];   // h as f16x2, 512 B
    __shared__ float xch[4096];                 // partials [q][gate][u], 16 KB
    int b = blockIdx.x, tt = threadIdx.x;
    int u = tt & 255, q = tt >> 8;
    int q8 = q * 8;

    const uint4* wsrc = (const uint4*)wp;

    // stage o-rows (768..1023) into LDS: wo4[d4*256 + r] = wp4[d4*1024 + 768 + r]
    {
        uint4* dst = (uint4*)wo;
        for (int i4 = tt; i4 < 8192; i4 += 1024) {
            int d4 = i4 >> 8, r = i4 & 255;
            dst[i4] = wsrc[d4 * 1024 + 768 + r];
        }
    }

    // 16 named + PINNED register weights: k-octets q8..q8+7 of rows u, 256+u
#define LDW(j)                                              \
    uint4 wi##j = wsrc[(q8 + j) * 1024 + u];                \
    uint4 wf##j = wsrc[(q8 + j) * 1024 + 256 + u];
    LDW(0) LDW(1) LDW(2) LDW(3) LDW(4) LDW(5) LDW(6) LDW(7)
#undef LDW
#define PIN(v) asm volatile("" : "+v"(v.x), "+v"(v.y), "+v"(v.z), "+v"(v.w))
    PIN(wi0); PIN(wi1); PIN(wi2); PIN(wi3);
    PIN(wi4); PIN(wi5); PIN(wi6); PIN(wi7);
    PIN(wf0); PIN(wf1); PIN(wf2); PIN(wf3);
    PIN(wf4); PIN(wf5); PIN(wf6); PIN(wf7);
#undef PIN

    // init h (packed f16x2) and per-unit state (q==0 threads only)
    if (tt < 128) {
        h2u[tt] = pack2_rne(h0[b * 256 + 2 * tt], h0[b * 256 + 2 * tt + 1]);
    }
    float c = 0.0f;
    float gv0 = 0.f, gv1 = 0.f, gv2 = 0.f, gv3 = 0.f;
    int dn = 0;
    const float* gbase = gi + (size_t)b * 1024;  // step stride 32*1024 floats
    if (q == 0) {
        c = c0[b * 256 + u];
        gv0 = gbase[u];
        gv1 = gbase[256 + u];
        gv2 = gbase[512 + u];
        gv3 = gbase[768 + u];
        dn = done[b];
    }
    __syncthreads();

    const uint4* h2u4 = (const uint4*)h2u;
    const uint4* wo4 = (const uint4*)wo;

    for (int step = 0; step < 64; ++step) {
        // stream g-gate weights from L2 through a laundered (non-hoistable)
        // base so the loads are issued fresh each step, not hoisted+spilled.
        int lz = 0;
        asm volatile("" : "+v"(lz));
        const uint4* gs = wsrc + lz;
#define LDG(j) uint4 wg##j = gs[(q8 + j) * 1024 + 512 + u];
        LDG(0) LDG(1) LDG(2) LDG(3) LDG(4) LDG(5) LDG(6) LDG(7)
#undef LDG

        // prefetch next step's gate inputs + done (q==0 waves, wave-uniform)
        float nx0 = 0.f, nx1 = 0.f, nx2 = 0.f, nx3 = 0.f;
        int dnn = 0;
        if (q == 0 && step < 63) {
            const float* gb = gbase + (size_t)(step + 1) * 32768;
            nx0 = gb[u];
            nx1 = gb[256 + u];
            nx2 = gb[512 + u];
            nx3 = gb[768 + u];
            dnn = done[(step + 1) * 32 + b];
        }

        float pI = 0.f, pF = 0.f, pG = 0.f, pO = 0.f;
        // streamed wg consumed LAST within each j so pinned-gate dot2s cover
        // the L2 latency of the g loads.
#define MV(j) {                                                         \
        uint4 ha = h2u4[q8 + j];      /* broadcast (uniform addr) */    \
        uint4 wv = wo4[(q8 + j) * 256 + u]; /* o row, conflict-free */  \
        pO = dot2(ha.x, wv.x, pO);    pO = dot2(ha.y, wv.y, pO);        \
        pO = dot2(ha.z, wv.z, pO);    pO = dot2(ha.w, wv.w, pO);        \
        pI = dot2(ha.x, wi##j.x, pI); pI = dot2(ha.y, wi##j.y, pI);     \
        pI = dot2(ha.z, wi##j.z, pI); pI = dot2(ha.w, wi##j.w, pI);     \
        pF = dot2(ha.x, wf##j.x, pF); pF = dot2(ha.y, wf##j.y, pF);     \
        pF = dot2(ha.z, wf##j.z, pF); pF = dot2(ha.w, wf##j.w, pF);     \
        pG = dot2(ha.x, wg##j.x, pG); pG = dot2(ha.y, wg##j.y, pG);     \
        pG = dot2(ha.z, wg##j.z, pG); pG = dot2(ha.w, wg##j.w, pG); }
        MV(0) MV(1) MV(2) MV(3) MV(4) MV(5) MV(6) MV(7)
#undef MV

        // post partials: xch[q*1024 + gate*256 + u]
        xch[q * 1024 + u] = pI;
        xch[q * 1024 + 256 + u] = pF;
        xch[q * 1024 + 512 + u] = pG;
        xch[q * 1024 + 768 + u] = pO;
        __syncthreads();  // partials visible; all h2u reads of this step done

        if (q == 0) {
            float sI = xch[u] + xch[1024 + u] + xch[2048 + u] + xch[3072 + u];
            float sF = xch[256 + u] + xch[1280 + u] + xch[2304 + u] + xch[3328 + u];
            float sG = xch[512 + u] + xch[1536 + u] + xch[2560 + u] + xch[3584 + u];
            float sO = xch[768 + u] + xch[1792 + u] + xch[2816 + u] + xch[3840 + u];
            float m = 1.0f - (float)dn;
            float g_i = gv0 + m * sI;
            float g_f = gv1 + m * sF;
            float g_g = gv2 + m * sG;
            float g_o = gv3 + m * sO;
            float si = 1.0f / (1.0f + __expf(-g_i));
            float sf = 1.0f / (1.0f + __expf(-g_f));
            float so = 1.0f / (1.0f + __expf(-g_o));
            float tg = fast_tanh(g_g);
            c = sf * (c * m) + si * tg;
            float hn = so * fast_tanh(c);
            out[((size_t)step * 32 + b) * 256 + u] = hn;
            float hn2 = __shfl_xor(hn, 1);
            if ((u & 1) == 0) {
                unsigned lo = f2h_bits(hn);
                unsigned hi = f2h_bits(hn2);
                h2u[u >> 1] = lo | (hi << 16);
            }
        }
        __syncthreads();  // new h + freed xch visible before next step

        gv0 = nx0; gv1 = nx1; gv2 = nx2; gv3 = nx3;
        dn = dnn;
    }
}

// ---------------------------------------------------------------------------
extern "C" void kernel_launch(void* const* d_in, const int* in_sizes, int n_in,
                              void* d_out, int out_size, void* d_ws, size_t ws_size,
                              hipStream_t stream) {
    const float* x    = (const float*)d_in[0];
    const int*   done = (const int*)d_in[1];
    const float* w1   = (const float*)d_in[2];
    const float* b1   = (const float*)d_in[3];
    const float* w2   = (const float*)d_in[4];
    const float* b2   = (const float*)d_in[5];
    const float* w3   = (const float*)d_in[6];
    const float* b3   = (const float*)d_in[7];
    const float* fcw  = (const float*)d_in[8];
    const float* fcb  = (const float*)d_in[9];
    const float* wih  = (const float*)d_in[10];
    const float* whh  = (const float*)d_in[11];
    const float* bih  = (const float*)d_in[12];
    const float* bhh  = (const float*)d_in[13];
    const float* h0   = (const float*)d_in[14];
    const float* c0   = (const float*)d_in[15];
    float* out = (float*)d_out;
    float* ws = (float*)d_ws;

    // workspace layout (float offsets):
    // z1u (f16): [0, 7,864,320) FLOATS of shorts -- (2048, 32, 15, 16)
    // z2:        [8,000,000, 12,718,592)
    // z3:        [0, 2,097,152)           (z1u dead after conv2)
    // feats:     [2,097,152, 3,145,728)
    // gi:        [3,145,728, 5,242,880)
    // w3t:       [13,000,000, +36,864)
    // w1p:       [13,100,000, +4,096)   (uint)
    // w2p:       [13,200,000, +16,384)  (uint)
    // wp (whh packed f16x2, uint[131072]): [13,300,000, 13,431,072)
    //   NOTE: wp MUST live past z1u's end (7,864,320) -- conv1 writes z1u
    //   after the pack kernels run. R9 had it at 5.5M and got clobbered.
    unsigned short* z1u = (unsigned short*)(ws + 0);
    float* z2    = ws + 8000000;
    float* z3    = ws + 0;
    float* feats = ws + 2097152;
    float* gi    = ws + 3145728;
    float* w3t   = ws + 13000000;
    unsigned* w1p = (unsigned*)(ws + 13100000);
    unsigned* w2p = (unsigned*)(ws + 13200000);
    unsigned* wp  = (unsigned*)(ws + 13300000);

    transpose_kernel<<<(64 * 576 + 255) / 256, 256, 0, stream>>>(w3, w3t, 64, 576);
    pack_whh_pairs_kernel<<<512, 256, 0, stream>>>(whh, wp);
    pack_w1_kernel<<<16, 256, 0, stream>>>(w1, w1p);
    pack_w2_kernel<<<64, 256, 0, stream>>>(w2, w2p);

    conv1_kernel<<<NIMG, 1024, 0, stream>>>(x, w1p, b1, z1u);
    conv2_kernel<<<NIMG / 2, 768, 0, stream>>>(z1u, w2p, b2, z2);
    conv3_kernel<<<NIMG / 4, 512, 0, stream>>>(z2, w3t, b3, z3);

    gemm_bt<<<dim3(512 / 64, NIMG / 64), 256, 0, stream>>>(z3, fcw, fcb, nullptr, feats,
                                                           NIMG, 512, 1024, 1);
    gemm_bt<<<dim3(1024 / 64, NIMG / 64), 256, 0, stream>>>(feats, wih, bih, bhh, gi,
                                                            NIMG, 1024, 512, 0);

    lstm_kernel<<<32, 1024, 0, stream>>>(gi, wp, done, h0, c0, out);
}

// Round 7
// 603.522 us; speedup vs baseline: 1.5209x; 1.5209x over previous
//
#include <hip/hip_runtime.h>
#include <math.h>

// ---------------------------------------------------------------------------
// RecurrentNatureCNN: conv1(8x8,s4) -> conv2(4x4,s2) -> conv3(3x3,s1) -> FC
//                     -> LSTM(T=64,B=32,H=256)
// N = T*B = 2048 images.
// R15: = R13 LSTM (exact revert of R14's pin/launder, which spilled: the
//      allocator holds a hard 64-VGPR target at 1024 thr and spills pinned
//      values) + done-mask skip. Reference: gates += m * (whh @ h) with
//      m = 1-done, done ~ Bernoulli(0.5) -> ~half the (step,env) matvecs
//      are dead work. dn is block-uniform -> clean uniform branch around
//      the matvec; remat'd weight loads sink into the branch and never
//      issue on masked steps. Streamed L2 bytes halve in expectation.
//      conv/GEMM stages unchanged from R8.
// ---------------------------------------------------------------------------

#define NIMG 2048

typedef _Float16 half2_t __attribute__((ext_vector_type(2)));
typedef __fp16 fp16x2_t __attribute__((ext_vector_type(2)));

__device__ inline unsigned short f2h_bits(float f) {
    union { _Float16 h; unsigned short u; } x;
    x.h = (_Float16)f;
    return x.u;
}

__device__ inline unsigned pack2_rne(float a, float b) {
    return (unsigned)f2h_bits(a) | ((unsigned)f2h_bits(b) << 16);
}

__device__ inline unsigned pack2_fast(float a, float b) {
#if __has_builtin(__builtin_amdgcn_cvt_pkrtz)
    union { fp16x2_t h; unsigned u; } x;
    x.h = __builtin_amdgcn_cvt_pkrtz(a, b);
    return x.u;
#else
    return pack2_rne(a, b);
#endif
}

__device__ inline float dot2(unsigned hu, unsigned wu, float acc) {
    union { unsigned u; half2_t h; } a, b;
    a.u = hu; b.u = wu;
#if __has_builtin(__builtin_amdgcn_fdot2)
    return __builtin_amdgcn_fdot2(a.h, b.h, acc, false);
#else
    return acc + (float)a.h.x * (float)b.h.x + (float)a.h.y * (float)b.h.y;
#endif
}

__device__ inline float fast_tanh(float x) {
    return 1.0f - 2.0f / (__expf(2.0f * x) + 1.0f);
}

// ---- generic small transpose: in (R,C) -> out (C,R) -----------------------
__global__ void transpose_kernel(const float* __restrict__ in, float* __restrict__ out,
                                 int R, int C) {
    int idx = blockIdx.x * 256 + threadIdx.x;
    if (idx < R * C) {
        int r = idx / C, c = idx - r * C;
        out[c * R + r] = in[idx];
    }
}

// ---- pack whh (1024,256) fp32 -> f16x2 pairs, uint4-interleaved by row -----
// As uint4: wp4[d4*1024 + row] = row's packed k = [d4*8, d4*8+8).
__global__ void pack_whh_pairs_kernel(const float* __restrict__ whh,
                                      unsigned* __restrict__ wp) {
    int idx = blockIdx.x * 256 + threadIdx.x;  // 0..131071
    if (idx >= 131072) return;
    int d4 = idx >> 12;
    int rem = idx & 4095;
    int row = rem >> 2;
    int j = idx & 3;
    int k0 = d4 * 8 + j * 2;
    const float* src = whh + (size_t)row * 256 + k0;
    wp[idx] = pack2_rne(src[0], src[1]);
}

// ---- pack w1 (32,4,8,8) fp32 -> f16x2 pairs along kx: w1p[oc][ic][ky][kxp] -
__global__ void pack_w1_kernel(const float* __restrict__ w1, unsigned* __restrict__ w1p) {
    int idx = blockIdx.x * 256 + threadIdx.x;  // 0..4095
    if (idx >= 4096) return;
    int oc = idx >> 7, rem = idx & 127;
    int ic = rem >> 5, ky = (rem >> 2) & 7, kxp = rem & 3;
    const float* src = w1 + (((size_t)oc * 4 + ic) * 8 + ky) * 8 + kxp * 2;
    w1p[idx] = pack2_rne(src[0], src[1]);
}

// ---- pack w2 (64,32,4,4) fp32 -> f16x2 pairs: w2p[(ic*4+ky)*2+kxp][oc] -----
__global__ void pack_w2_kernel(const float* __restrict__ w2, unsigned* __restrict__ w2p) {
    int idx = blockIdx.x * 256 + threadIdx.x;  // 0..16383
    if (idx >= 16384) return;
    int p = idx >> 6, oc = idx & 63;
    int ic = p >> 3, ky = (p >> 1) & 3, kxp = p & 1;
    const float* src = w2 + (size_t)oc * 512 + ic * 16 + ky * 4 + kxp * 2;
    w2p[idx] = pack2_rne(src[0], src[1]);
}

// ---- conv1: x (n,4,64,64)/255 -> relu -> z1 f16 (n,32,15,16 padded) --------
__global__ __launch_bounds__(1024) void conv1_kernel(const float* __restrict__ x,
                                                     const unsigned* __restrict__ w1p,
                                                     const float* __restrict__ b,
                                                     unsigned short* __restrict__ z1) {
    __shared__ unsigned short xs[4 * 64 * 64];  // f16, 32768 B
    int n = blockIdx.x;
    int tid = threadIdx.x;
    const float* xp = x + (size_t)n * 16384;
    const float inv = 1.0f / 255.0f;
    for (int i = tid * 4; i < 16384; i += 4096) {
        float4 v = *(const float4*)(xp + i);
        uint2 q;
        q.x = pack2_fast(v.x * inv, v.y * inv);
        q.y = pack2_fast(v.z * inv, v.w * inv);
        *(uint2*)&xs[i] = q;
    }
    __syncthreads();
    int lane = tid & 63, wave = tid >> 6;
    int gg = __builtin_amdgcn_readfirstlane(wave & 3);
    int pos = (wave >> 2) * 64 + lane;  // 0..255
    if (pos < 225) {
        int oy = pos / 15, ox = pos - oy * 15;
        float acc[8];
        const float* bp = b + gg * 8;
#pragma unroll
        for (int u = 0; u < 8; ++u) acc[u] = bp[u];
        for (int ic = 0; ic < 4; ++ic) {
#pragma unroll
            for (int ky = 0; ky < 8; ++ky) {
                const unsigned short* row = &xs[(ic * 64 + oy * 4 + ky) * 64 + ox * 4];
                uint2 qa = *(const uint2*)row;        // cols +0..3 (2 pairs)
                uint2 qb = *(const uint2*)(row + 4);  // cols +4..7 (2 pairs)
                const unsigned* wp = w1p + ((((gg * 8) * 4 + ic) * 8 + ky) * 4);
#pragma unroll
                for (int u = 0; u < 8; ++u) {
                    const unsigned* wu = wp + u * 128;  // (oc stride 4*8*4)
                    acc[u] = dot2(qa.x, wu[0], acc[u]);
                    acc[u] = dot2(qa.y, wu[1], acc[u]);
                    acc[u] = dot2(qb.x, wu[2], acc[u]);
                    acc[u] = dot2(qb.y, wu[3], acc[u]);
                }
            }
        }
        unsigned short* op = z1 + (size_t)n * 7680 + (gg * 8) * 240 + oy * 16 + ox;
#pragma unroll
        for (int u = 0; u < 8; ++u) op[u * 240] = f2h_bits(fmaxf(acc[u], 0.0f));
    }
}

// ---- conv2: z1 f16 (n,32,15,16) -> relu -> z2 fp32 (n,64,6,6) --------------
__global__ __launch_bounds__(768) void conv2_kernel(const unsigned short* __restrict__ z1,
                                                    const unsigned* __restrict__ w2p,
                                                    const float* __restrict__ bias,
                                                    float* __restrict__ out) {
    __shared__ unsigned short xs[2][32 * 15 * 16];  // f16, 30720 B
    int tid = threadIdx.x;
    int n0 = blockIdx.x * 2;
#pragma unroll
    for (int img = 0; img < 2; ++img) {
        const unsigned* src = (const unsigned*)(z1 + (size_t)(n0 + img) * 7680);
        unsigned* dst = (unsigned*)xs[img];
        for (int i = tid; i < 3840; i += 768) dst[i] = src[i];
    }
    __syncthreads();
    int lane = tid & 63, wave = tid >> 6;  // wave 0..11
    int img = wave / 6;
    int oy = wave - img * 6;
    int n = n0 + img;
    float bv = bias[lane];
    float* op = out + (size_t)n * 2304 + lane * 36;
    float acc[6];
#pragma unroll
    for (int u = 0; u < 6; ++u) acc[u] = bv;
    for (int ic = 0; ic < 32; ++ic) {
#pragma unroll
        for (int ky = 0; ky < 4; ++ky) {
            const unsigned short* row = &xs[img][(ic * 15 + oy * 2 + ky) * 16];
            uint4 pa = *(const uint4*)row;        // pairs 0..3  (cols 0..7)
            uint4 pb = *(const uint4*)(row + 8);  // pairs 4..7  (cols 8..15)
            unsigned p[8] = {pa.x, pa.y, pa.z, pa.w, pb.x, pb.y, pb.z, pb.w};
            const unsigned* wpp = w2p + ((ic * 4 + ky) * 2) * 64 + lane;
            unsigned wa = wpp[0];   // kx 0,1
            unsigned wb = wpp[64];  // kx 2,3
#pragma unroll
            for (int u = 0; u < 6; ++u) {
                acc[u] = dot2(p[u], wa, acc[u]);
                acc[u] = dot2(p[u + 1], wb, acc[u]);
            }
        }
    }
#pragma unroll
    for (int u = 0; u < 6; ++u) op[oy * 6 + u] = fmaxf(acc[u], 0.0f);
}

// ---- conv3: z2 (n,64,6,6) -> relu -> (n,64,4,4)  (fp32, unchanged) ---------
__global__ __launch_bounds__(512) void conv3_kernel(const float* __restrict__ x,
                                                    const float* __restrict__ wt,
                                                    const float* __restrict__ bias,
                                                    float* __restrict__ out) {
    __shared__ float xs[4][64 * 6 * 8];  // 49152 B
    int tid = threadIdx.x;
    int n0 = blockIdx.x * 4;
    for (int img = 0; img < 4; ++img) {
        const float* src = x + (size_t)(n0 + img) * 2304;
        for (int s = tid; s < 2304; s += 512) {
            int ic = s / 36;
            int rem = s - ic * 36;
            int r = rem / 6;
            int c = rem - r * 6;
            xs[img][(ic * 6 + r) * 8 + c] = src[s];
        }
    }
    __syncthreads();
    int lane = tid & 63, wave = tid >> 6;  // 0..7
    int img = wave >> 1;
    int half = wave & 1;
    int n = n0 + img;
    float bv = bias[lane];
    float* op = out + (size_t)n * 1024 + lane * 16;
    for (int q = 0; q < 2; ++q) {
        int oy = half * 2 + q;
        float acc[4];
#pragma unroll
        for (int u = 0; u < 4; ++u) acc[u] = bv;
        for (int ic = 0; ic < 64; ++ic) {
#pragma unroll
            for (int ky = 0; ky < 3; ++ky) {
                const float* xrow = &xs[img][(ic * 6 + oy + ky) * 8];
                float xr[8];
                *(float4*)&xr[0] = *(const float4*)&xrow[0];
                *(float4*)&xr[4] = *(const float4*)&xrow[4];
                const float* wp = wt + ((ic * 3 + ky) * 3) * 64 + lane;
#pragma unroll
                for (int kx = 0; kx < 3; ++kx) {
                    float wv = wp[kx * 64];
#pragma unroll
                    for (int u = 0; u < 4; ++u) acc[u] += xr[u + kx] * wv;
                }
            }
        }
#pragma unroll
        for (int u = 0; u < 4; ++u) op[oy * 4 + u] = fmaxf(acc[u], 0.0f);
    }
}

// ---- GEMM: C(M,N) = [relu]( A(M,K) @ B(N,K)^T + bias [+ bias2] ) -----------
__global__ __launch_bounds__(256) void gemm_bt(const float* __restrict__ A,
                                               const float* __restrict__ B,
                                               const float* __restrict__ bias,
                                               const float* __restrict__ bias2,
                                               float* __restrict__ C,
                                               int M, int N, int K, int relu) {
    __shared__ float As[16][68];
    __shared__ float Bs[16][68];
    int tid = threadIdx.x;
    int m0 = blockIdx.y * 64, n0 = blockIdx.x * 64;
    int tx = tid & 15, ty = tid >> 4;
    int lr = tid >> 2;
    int lk = (tid & 3) * 4;
    const float* Ap = A + (size_t)(m0 + lr) * K + lk;
    const float* Bp = B + (size_t)(n0 + lr) * K + lk;
    float acc[4][4];
#pragma unroll
    for (int i = 0; i < 4; ++i)
#pragma unroll
        for (int j = 0; j < 4; ++j) acc[i][j] = 0.0f;

    for (int k0 = 0; k0 < K; k0 += 16) {
        float4 av = *(const float4*)(Ap + k0);
        float4 bv = *(const float4*)(Bp + k0);
        __syncthreads();
        As[lk + 0][lr] = av.x;
        As[lk + 1][lr] = av.y;
        As[lk + 2][lr] = av.z;
        As[lk + 3][lr] = av.w;
        Bs[lk + 0][lr] = bv.x;
        Bs[lk + 1][lr] = bv.y;
        Bs[lk + 2][lr] = bv.z;
        Bs[lk + 3][lr] = bv.w;
        __syncthreads();
#pragma unroll
        for (int kk = 0; kk < 16; ++kk) {
            float a[4], b[4];
            *(float4*)a = *(const float4*)&As[kk][ty * 4];
            *(float4*)b = *(const float4*)&Bs[kk][tx * 4];
#pragma unroll
            for (int i = 0; i < 4; ++i)
#pragma unroll
                for (int j = 0; j < 4; ++j) acc[i][j] += a[i] * b[j];
        }
    }
    float bb[4];
#pragma unroll
    for (int j = 0; j < 4; ++j) {
        float v = bias[n0 + tx * 4 + j];
        if (bias2) v += bias2[n0 + tx * 4 + j];
        bb[j] = v;
    }
#pragma unroll
    for (int i = 0; i < 4; ++i) {
        float4 o;
        o.x = acc[i][0] + bb[0];
        o.y = acc[i][1] + bb[1];
        o.z = acc[i][2] + bb[2];
        o.w = acc[i][3] + bb[3];
        if (relu) {
            o.x = fmaxf(o.x, 0.0f);
            o.y = fmaxf(o.y, 0.0f);
            o.z = fmaxf(o.z, 0.0f);
            o.w = fmaxf(o.w, 0.0f);
        }
        *(float4*)&C[(size_t)(m0 + ty * 4 + i) * N + n0 + tx * 4] = o;
    }
}

// ---- LSTM R15: R13 structure + done-mask skip ------------------------------
// 32 blocks (one per env), 1024 threads. Thread (u = tt&255, q = tt>>8) owns
// k-quarter q of gate rows u (i), 256+u (f), 512+u (g): 24 named uint4
// (compiler remats these loads into the step loop -> L2 stream; that is the
// measured 6.2K cyc/step floor). O-gate row u in LDS (128 KB). Partials
// reduced over q via 16 KB LDS exchange; q==0 waves do the c/h update.
// NEW: done[step,env] is block-uniform; when dn==1 the reference multiplies
// the whole whh@h term by 0 -> skip the matvec AND its weight streaming.
// ~50% of steps skip -> expected streamed bytes halve.
__global__ __launch_bounds__(1024) void lstm_kernel(const float* __restrict__ gi,
                                                    const unsigned* __restrict__ wp,
                                                    const int* __restrict__ done,
                                                    const float* __restrict__ h0,
                                                    const float* __restrict__ c0,
                                                    float* __restrict__ out) {
    __shared__ alignas(16) unsigned wo[32768];  // o-rows f16x2: [d4][256][4], 128 KB
    __shared__ alignas(16) unsigned h2u[128];   // h as f16x2, 512 B
    __shared__ float xch[4096];                 // partials [q][gate][u], 16 KB
    int b = blockIdx.x, tt = threadIdx.x;
    int u = tt & 255, q = tt >> 8;
    int q8 = q * 8;

    const uint4* wsrc = (const uint4*)wp;

    // stage o-rows (768..1023) into LDS: wo4[d4*256 + r] = wp4[d4*1024 + 768 + r]
    {
        uint4* dst = (uint4*)wo;
        for (int i4 = tt; i4 < 8192; i4 += 1024) {
            int d4 = i4 >> 8, r = i4 & 255;
            dst[i4] = wsrc[d4 * 1024 + 768 + r];
        }
    }

    // 24 named register weights: k-octets q8..q8+7 of rows u / 256+u / 512+u
    // (compiler remats these into the loop; with the dn-branch they only
    // issue on unmasked steps)
#define LDW(j)                                              \
    uint4 wi##j = wsrc[(q8 + j) * 1024 + u];                \
    uint4 wf##j = wsrc[(q8 + j) * 1024 + 256 + u];          \
    uint4 wg##j = wsrc[(q8 + j) * 1024 + 512 + u];
    LDW(0) LDW(1) LDW(2) LDW(3) LDW(4) LDW(5) LDW(6) LDW(7)
#undef LDW

    // init h (packed f16x2) and per-unit state
    if (tt < 128) {
        h2u[tt] = pack2_rne(h0[b * 256 + 2 * tt], h0[b * 256 + 2 * tt + 1]);
    }
    float c = 0.0f;
    float gv0 = 0.f, gv1 = 0.f, gv2 = 0.f, gv3 = 0.f;
    int dn = done[b];  // ALL threads track dn (block-uniform)
    const float* gbase = gi + (size_t)b * 1024;  // step stride 32*1024 floats
    if (q == 0) {
        c = c0[b * 256 + u];
        gv0 = gbase[u];
        gv1 = gbase[256 + u];
        gv2 = gbase[512 + u];
        gv3 = gbase[768 + u];
    }
    __syncthreads();

    const uint4* h2u4 = (const uint4*)h2u;
    const uint4* wo4 = (const uint4*)wo;

    for (int step = 0; step < 64; ++step) {
        // prefetch next step's done (all threads, uniform) + gate inputs (q==0)
        int dnn = 0;
        if (step < 63) dnn = done[(step + 1) * 32 + b];
        float nx0 = 0.f, nx1 = 0.f, nx2 = 0.f, nx3 = 0.f;
        if (q == 0 && step < 63) {
            const float* gb = gbase + (size_t)(step + 1) * 32768;
            nx0 = gb[u];
            nx1 = gb[256 + u];
            nx2 = gb[512 + u];
            nx3 = gb[768 + u];
        }

        float pI = 0.f, pF = 0.f, pG = 0.f, pO = 0.f;
        if (!dn) {  // m==1: recurrent term live -> do the matvec
#define MV(j) {                                                         \
        uint4 ha = h2u4[q8 + j];      /* broadcast (uniform addr) */    \
        uint4 wv = wo4[(q8 + j) * 256 + u]; /* o row, conflict-free */  \
        pI = dot2(ha.x, wi##j.x, pI); pI = dot2(ha.y, wi##j.y, pI);     \
        pI = dot2(ha.z, wi##j.z, pI); pI = dot2(ha.w, wi##j.w, pI);     \
        pF = dot2(ha.x, wf##j.x, pF); pF = dot2(ha.y, wf##j.y, pF);     \
        pF = dot2(ha.z, wf##j.z, pF); pF = dot2(ha.w, wf##j.w, pF);     \
        pG = dot2(ha.x, wg##j.x, pG); pG = dot2(ha.y, wg##j.y, pG);     \
        pG = dot2(ha.z, wg##j.z, pG); pG = dot2(ha.w, wg##j.w, pG);     \
        pO = dot2(ha.x, wv.x, pO);    pO = dot2(ha.y, wv.y, pO);        \
        pO = dot2(ha.z, wv.z, pO);    pO = dot2(ha.w, wv.w, pO); }
            MV(0) MV(1) MV(2) MV(3) MV(4) MV(5) MV(6) MV(7)
#undef MV
        }

        // post partials: xch[q*1024 + gate*256 + u]
        xch[q * 1024 + u] = pI;
        xch[q * 1024 + 256 + u] = pF;
        xch[q * 1024 + 512 + u] = pG;
        xch[q * 1024 + 768 + u] = pO;
        __syncthreads();  // partials visible; all h2u reads of this step done

        if (q == 0) {
            float m = 1.0f - (float)dn;
            float sI = xch[u] + xch[1024 + u] + xch[2048 + u] + xch[3072 + u];
            float sF = xch[256 + u] + xch[1280 + u] + xch[2304 + u] + xch[3328 + u];
            float sG = xch[512 + u] + xch[1536 + u] + xch[2560 + u] + xch[3584 + u];
            float sO = xch[768 + u] + xch[1792 + u] + xch[2816 + u] + xch[3840 + u];
            float g_i = gv0 + m * sI;
            float g_f = gv1 + m * sF;
            float g_g = gv2 + m * sG;
            float g_o = gv3 + m * sO;
            float si = 1.0f / (1.0f + __expf(-g_i));
            float sf = 1.0f / (1.0f + __expf(-g_f));
            float so = 1.0f / (1.0f + __expf(-g_o));
            float tg = fast_tanh(g_g);
            c = sf * (c * m) + si * tg;
            float hn = so * fast_tanh(c);
            out[((size_t)step * 32 + b) * 256 + u] = hn;
            float hn2 = __shfl_xor(hn, 1);
            if ((u & 1) == 0) {
                unsigned lo = f2h_bits(hn);
                unsigned hi = f2h_bits(hn2);
                h2u[u >> 1] = lo | (hi << 16);
            }
        }
        __syncthreads();  // new h + freed xch visible before next step

        gv0 = nx0; gv1 = nx1; gv2 = nx2; gv3 = nx3;
        dn = dnn;
    }
}

// ---------------------------------------------------------------------------
extern "C" void kernel_launch(void* const* d_in, const int* in_sizes, int n_in,
                              void* d_out, int out_size, void* d_ws, size_t ws_size,
                              hipStream_t stream) {
    const float* x    = (const float*)d_in[0];
    const int*   done = (const int*)d_in[1];
    const float* w1   = (const float*)d_in[2];
    const float* b1   = (const float*)d_in[3];
    const float* w2   = (const float*)d_in[4];
    const float* b2   = (const float*)d_in[5];
    const float* w3   = (const float*)d_in[6];
    const float* b3   = (const float*)d_in[7];
    const float* fcw  = (const float*)d_in[8];
    const float* fcb  = (const float*)d_in[9];
    const float* wih  = (const float*)d_in[10];
    const float* whh  = (const float*)d_in[11];
    const float* bih  = (const float*)d_in[12];
    const float* bhh  = (const float*)d_in[13];
    const float* h0   = (const float*)d_in[14];
    const float* c0   = (const float*)d_in[15];
    float* out = (float*)d_out;
    float* ws = (float*)d_ws;

    // workspace layout (float offsets):
    // z1u (f16): [0, 7,864,320) FLOATS of shorts -- (2048, 32, 15, 16)
    // z2:        [8,000,000, 12,718,592)
    // z3:        [0, 2,097,152)           (z1u dead after conv2)
    // feats:     [2,097,152, 3,145,728)
    // gi:        [3,145,728, 5,242,880)
    // w3t:       [13,000,000, +36,864)
    // w1p:       [13,100,000, +4,096)   (uint)
    // w2p:       [13,200,000, +16,384)  (uint)
    // wp (whh packed f16x2, uint[131072]): [13,300,000, 13,431,072)
    //   NOTE: wp MUST live past z1u's end (7,864,320) -- conv1 writes z1u
    //   after the pack kernels run. R9 had it at 5.5M and got clobbered.
    unsigned short* z1u = (unsigned short*)(ws + 0);
    float* z2    = ws + 8000000;
    float* z3    = ws + 0;
    float* feats = ws + 2097152;
    float* gi    = ws + 3145728;
    float* w3t   = ws + 13000000;
    unsigned* w1p = (unsigned*)(ws + 13100000);
    unsigned* w2p = (unsigned*)(ws + 13200000);
    unsigned* wp  = (unsigned*)(ws + 13300000);

    transpose_kernel<<<(64 * 576 + 255) / 256, 256, 0, stream>>>(w3, w3t, 64, 576);
    pack_whh_pairs_kernel<<<512, 256, 0, stream>>>(whh, wp);
    pack_w1_kernel<<<16, 256, 0, stream>>>(w1, w1p);
    pack_w2_kernel<<<64, 256, 0, stream>>>(w2, w2p);

    conv1_kernel<<<NIMG, 1024, 0, stream>>>(x, w1p, b1, z1u);
    conv2_kernel<<<NIMG / 2, 768, 0, stream>>>(z1u, w2p, b2, z2);
    conv3_kernel<<<NIMG / 4, 512, 0, stream>>>(z2, w3t, b3, z3);

    gemm_bt<<<dim3(512 / 64, NIMG / 64), 256, 0, stream>>>(z3, fcw, fcb, nullptr, feats,
                                                           NIMG, 512, 1024, 1);
    gemm_bt<<<dim3(1024 / 64, NIMG / 64), 256, 0, stream>>>(feats, wih, bih, bhh, gi,
                                                            NIMG, 1024, 512, 0);

    lstm_kernel<<<32, 1024, 0, stream>>>(gi, wp, done, h0, c0, out);
}

// Round 8
// 566.013 us; speedup vs baseline: 1.6217x; 1.0663x over previous
//
#include <hip/hip_runtime.h>
#include <math.h>

// ---------------------------------------------------------------------------
// RecurrentNatureCNN: conv1(8x8,s4) -> conv2(4x4,s2) -> conv3(3x3,s1) -> FC
//                     -> LSTM(T=64,B=32,H=256)
// N = T*B = 2048 images.
// R16: = R15 (lstm kept: 119 us, mask-skip + L2-stream floor) with both
//      GEMMs converted to f16-pair v_dot2_f32_f16 + register prefetch.
//      gemm1/2 were fp32 FMA at 1 block/CU (1 wave/SIMD): exposed L2
//      latency per K-step + 1 MAC/inst. f16 pairs halve staging bytes and
//      K-iterations; prefetch hides L2 latency under the dot2 burst.
//      conv3 writes z3h (f16 pairs) directly; gemm1 emits featsh pairs;
//      fcw/wih pair-packed after conv3 into the then-dead z2 region.
//      conv1/conv2/conv3 core + LSTM unchanged from R15.
// ---------------------------------------------------------------------------

#define NIMG 2048

typedef _Float16 half2_t __attribute__((ext_vector_type(2)));
typedef __fp16 fp16x2_t __attribute__((ext_vector_type(2)));

__device__ inline unsigned short f2h_bits(float f) {
    union { _Float16 h; unsigned short u; } x;
    x.h = (_Float16)f;
    return x.u;
}

__device__ inline unsigned pack2_rne(float a, float b) {
    return (unsigned)f2h_bits(a) | ((unsigned)f2h_bits(b) << 16);
}

__device__ inline unsigned pack2_fast(float a, float b) {
#if __has_builtin(__builtin_amdgcn_cvt_pkrtz)
    union { fp16x2_t h; unsigned u; } x;
    x.h = __builtin_amdgcn_cvt_pkrtz(a, b);
    return x.u;
#else
    return pack2_rne(a, b);
#endif
}

__device__ inline float dot2(unsigned hu, unsigned wu, float acc) {
    union { unsigned u; half2_t h; } a, b;
    a.u = hu; b.u = wu;
#if __has_builtin(__builtin_amdgcn_fdot2)
    return __builtin_amdgcn_fdot2(a.h, b.h, acc, false);
#else
    return acc + (float)a.h.x * (float)b.h.x + (float)a.h.y * (float)b.h.y;
#endif
}

__device__ inline float fast_tanh(float x) {
    return 1.0f - 2.0f / (__expf(2.0f * x) + 1.0f);
}

// ---- generic small transpose: in (R,C) -> out (C,R) -----------------------
__global__ void transpose_kernel(const float* __restrict__ in, float* __restrict__ out,
                                 int R, int C) {
    int idx = blockIdx.x * 256 + threadIdx.x;
    if (idx < R * C) {
        int r = idx / C, c = idx - r * C;
        out[c * R + r] = in[idx];
    }
}

// ---- generic pair-pack: dst[i] = f16x2(src[2i], src[2i+1]) -----------------
// (valid for any row-major matrix packed along its contiguous K dim)
__global__ void pack_pairs_kernel(const float* __restrict__ src,
                                  unsigned* __restrict__ dst, int total) {
    int idx = blockIdx.x * 256 + threadIdx.x;
    if (idx < total) {
        const float* s = src + (size_t)idx * 2;
        dst[idx] = pack2_rne(s[0], s[1]);
    }
}

// ---- pack whh (1024,256) fp32 -> f16x2 pairs, uint4-interleaved by row -----
// As uint4: wp4[d4*1024 + row] = row's packed k = [d4*8, d4*8+8).
__global__ void pack_whh_pairs_kernel(const float* __restrict__ whh,
                                      unsigned* __restrict__ wp) {
    int idx = blockIdx.x * 256 + threadIdx.x;  // 0..131071
    if (idx >= 131072) return;
    int d4 = idx >> 12;
    int rem = idx & 4095;
    int row = rem >> 2;
    int j = idx & 3;
    int k0 = d4 * 8 + j * 2;
    const float* src = whh + (size_t)row * 256 + k0;
    wp[idx] = pack2_rne(src[0], src[1]);
}

// ---- pack w1 (32,4,8,8) fp32 -> f16x2 pairs along kx: w1p[oc][ic][ky][kxp] -
__global__ void pack_w1_kernel(const float* __restrict__ w1, unsigned* __restrict__ w1p) {
    int idx = blockIdx.x * 256 + threadIdx.x;  // 0..4095
    if (idx >= 4096) return;
    int oc = idx >> 7, rem = idx & 127;
    int ic = rem >> 5, ky = (rem >> 2) & 7, kxp = rem & 3;
    const float* src = w1 + (((size_t)oc * 4 + ic) * 8 + ky) * 8 + kxp * 2;
    w1p[idx] = pack2_rne(src[0], src[1]);
}

// ---- pack w2 (64,32,4,4) fp32 -> f16x2 pairs: w2p[(ic*4+ky)*2+kxp][oc] -----
__global__ void pack_w2_kernel(const float* __restrict__ w2, unsigned* __restrict__ w2p) {
    int idx = blockIdx.x * 256 + threadIdx.x;  // 0..16383
    if (idx >= 16384) return;
    int p = idx >> 6, oc = idx & 63;
    int ic = p >> 3, ky = (p >> 1) & 3, kxp = p & 1;
    const float* src = w2 + (size_t)oc * 512 + ic * 16 + ky * 4 + kxp * 2;
    w2p[idx] = pack2_rne(src[0], src[1]);
}

// ---- conv1: x (n,4,64,64)/255 -> relu -> z1 f16 (n,32,15,16 padded) --------
__global__ __launch_bounds__(1024) void conv1_kernel(const float* __restrict__ x,
                                                     const unsigned* __restrict__ w1p,
                                                     const float* __restrict__ b,
                                                     unsigned short* __restrict__ z1) {
    __shared__ unsigned short xs[4 * 64 * 64];  // f16, 32768 B
    int n = blockIdx.x;
    int tid = threadIdx.x;
    const float* xp = x + (size_t)n * 16384;
    const float inv = 1.0f / 255.0f;
    for (int i = tid * 4; i < 16384; i += 4096) {
        float4 v = *(const float4*)(xp + i);
        uint2 q;
        q.x = pack2_fast(v.x * inv, v.y * inv);
        q.y = pack2_fast(v.z * inv, v.w * inv);
        *(uint2*)&xs[i] = q;
    }
    __syncthreads();
    int lane = tid & 63, wave = tid >> 6;
    int gg = __builtin_amdgcn_readfirstlane(wave & 3);
    int pos = (wave >> 2) * 64 + lane;  // 0..255
    if (pos < 225) {
        int oy = pos / 15, ox = pos - oy * 15;
        float acc[8];
        const float* bp = b + gg * 8;
#pragma unroll
        for (int u = 0; u < 8; ++u) acc[u] = bp[u];
        for (int ic = 0; ic < 4; ++ic) {
#pragma unroll
            for (int ky = 0; ky < 8; ++ky) {
                const unsigned short* row = &xs[(ic * 64 + oy * 4 + ky) * 64 + ox * 4];
                uint2 qa = *(const uint2*)row;        // cols +0..3 (2 pairs)
                uint2 qb = *(const uint2*)(row + 4);  // cols +4..7 (2 pairs)
                const unsigned* wp = w1p + ((((gg * 8) * 4 + ic) * 8 + ky) * 4);
#pragma unroll
                for (int u = 0; u < 8; ++u) {
                    const unsigned* wu = wp + u * 128;  // (oc stride 4*8*4)
                    acc[u] = dot2(qa.x, wu[0], acc[u]);
                    acc[u] = dot2(qa.y, wu[1], acc[u]);
                    acc[u] = dot2(qb.x, wu[2], acc[u]);
                    acc[u] = dot2(qb.y, wu[3], acc[u]);
                }
            }
        }
        unsigned short* op = z1 + (size_t)n * 7680 + (gg * 8) * 240 + oy * 16 + ox;
#pragma unroll
        for (int u = 0; u < 8; ++u) op[u * 240] = f2h_bits(fmaxf(acc[u], 0.0f));
    }
}

// ---- conv2: z1 f16 (n,32,15,16) -> relu -> z2 fp32 (n,64,6,6) --------------
__global__ __launch_bounds__(768) void conv2_kernel(const unsigned short* __restrict__ z1,
                                                    const unsigned* __restrict__ w2p,
                                                    const float* __restrict__ bias,
                                                    float* __restrict__ out) {
    __shared__ unsigned short xs[2][32 * 15 * 16];  // f16, 30720 B
    int tid = threadIdx.x;
    int n0 = blockIdx.x * 2;
#pragma unroll
    for (int img = 0; img < 2; ++img) {
        const unsigned* src = (const unsigned*)(z1 + (size_t)(n0 + img) * 7680);
        unsigned* dst = (unsigned*)xs[img];
        for (int i = tid; i < 3840; i += 768) dst[i] = src[i];
    }
    __syncthreads();
    int lane = tid & 63, wave = tid >> 6;  // wave 0..11
    int img = wave / 6;
    int oy = wave - img * 6;
    int n = n0 + img;
    float bv = bias[lane];
    float* op = out + (size_t)n * 2304 + lane * 36;
    float acc[6];
#pragma unroll
    for (int u = 0; u < 6; ++u) acc[u] = bv;
    for (int ic = 0; ic < 32; ++ic) {
#pragma unroll
        for (int ky = 0; ky < 4; ++ky) {
            const unsigned short* row = &xs[img][(ic * 15 + oy * 2 + ky) * 16];
            uint4 pa = *(const uint4*)row;        // pairs 0..3  (cols 0..7)
            uint4 pb = *(const uint4*)(row + 8);  // pairs 4..7  (cols 8..15)
            unsigned p[8] = {pa.x, pa.y, pa.z, pa.w, pb.x, pb.y, pb.z, pb.w};
            const unsigned* wpp = w2p + ((ic * 4 + ky) * 2) * 64 + lane;
            unsigned wa = wpp[0];   // kx 0,1
            unsigned wb = wpp[64];  // kx 2,3
#pragma unroll
            for (int u = 0; u < 6; ++u) {
                acc[u] = dot2(p[u], wa, acc[u]);
                acc[u] = dot2(p[u + 1], wb, acc[u]);
            }
        }
    }
#pragma unroll
    for (int u = 0; u < 6; ++u) op[oy * 6 + u] = fmaxf(acc[u], 0.0f);
}

// ---- conv3: z2 (n,64,6,6) -> relu -> z3h f16-pairs (n, 512 uints) ----------
// feature index = oc*16 + oy*4 + ox; pairs along feature (= GEMM K) dim.
__global__ __launch_bounds__(512) void conv3_kernel(const float* __restrict__ x,
                                                    const float* __restrict__ wt,
                                                    const float* __restrict__ bias,
                                                    unsigned* __restrict__ outp) {
    __shared__ float xs[4][64 * 6 * 8];  // 49152 B
    int tid = threadIdx.x;
    int n0 = blockIdx.x * 4;
    for (int img = 0; img < 4; ++img) {
        const float* src = x + (size_t)(n0 + img) * 2304;
        for (int s = tid; s < 2304; s += 512) {
            int ic = s / 36;
            int rem = s - ic * 36;
            int r = rem / 6;
            int c = rem - r * 6;
            xs[img][(ic * 6 + r) * 8 + c] = src[s];
        }
    }
    __syncthreads();
    int lane = tid & 63, wave = tid >> 6;  // 0..7
    int img = wave >> 1;
    int half = wave & 1;
    int n = n0 + img;
    float bv = bias[lane];
    unsigned* op = outp + (size_t)n * 512 + lane * 8;
    for (int q = 0; q < 2; ++q) {
        int oy = half * 2 + q;
        float acc[4];
#pragma unroll
        for (int u = 0; u < 4; ++u) acc[u] = bv;
        for (int ic = 0; ic < 64; ++ic) {
#pragma unroll
            for (int ky = 0; ky < 3; ++ky) {
                const float* xrow = &xs[img][(ic * 6 + oy + ky) * 8];
                float xr[8];
                *(float4*)&xr[0] = *(const float4*)&xrow[0];
                *(float4*)&xr[4] = *(const float4*)&xrow[4];
                const float* wp = wt + ((ic * 3 + ky) * 3) * 64 + lane;
#pragma unroll
                for (int kx = 0; kx < 3; ++kx) {
                    float wv = wp[kx * 64];
#pragma unroll
                    for (int u = 0; u < 4; ++u) acc[u] += xr[u + kx] * wv;
                }
            }
        }
        float a0 = fmaxf(acc[0], 0.0f), a1 = fmaxf(acc[1], 0.0f);
        float a2 = fmaxf(acc[2], 0.0f), a3 = fmaxf(acc[3], 0.0f);
        op[oy * 2 + 0] = pack2_rne(a0, a1);
        op[oy * 2 + 1] = pack2_rne(a2, a3);
    }
}

// ---- GEMM f16: C(M,N) = [relu]( A @ B^T + bias [+bias2] ), A/B f16 pairs ---
// A (M, Kp) uints, B (N, Kp) uints (pairs along K). Writes C fp32 (if
// non-null) and/or Ch f16-pairs along N (if non-null). Register prefetch of
// the next K-tile issues right after the barrier, hiding L2 latency under
// the 256-dot2 compute burst.
__global__ __launch_bounds__(256) void gemm_bt_h(const unsigned* __restrict__ A,
                                                 const unsigned* __restrict__ B,
                                                 const float* __restrict__ bias,
                                                 const float* __restrict__ bias2,
                                                 float* __restrict__ C,
                                                 unsigned* __restrict__ Ch,
                                                 int M, int N, int Kp, int relu) {
    __shared__ unsigned As[16][66];
    __shared__ unsigned Bs[16][66];
    int tid = threadIdx.x;
    int m0 = blockIdx.y * 64, n0 = blockIdx.x * 64;
    int tx = tid & 15, ty = tid >> 4;
    int lr = tid >> 2;
    int lk = (tid & 3) * 4;
    const unsigned* Ap = A + (size_t)(m0 + lr) * Kp + lk;
    const unsigned* Bp = B + (size_t)(n0 + lr) * Kp + lk;
    float acc[4][4];
#pragma unroll
    for (int i = 0; i < 4; ++i)
#pragma unroll
        for (int j = 0; j < 4; ++j) acc[i][j] = 0.0f;

    uint4 av = *(const uint4*)Ap;
    uint4 bv = *(const uint4*)Bp;
    for (int k0 = 0; k0 < Kp; k0 += 16) {
        __syncthreads();
        As[lk + 0][lr] = av.x;
        As[lk + 1][lr] = av.y;
        As[lk + 2][lr] = av.z;
        As[lk + 3][lr] = av.w;
        Bs[lk + 0][lr] = bv.x;
        Bs[lk + 1][lr] = bv.y;
        Bs[lk + 2][lr] = bv.z;
        Bs[lk + 3][lr] = bv.w;
        __syncthreads();
        if (k0 + 16 < Kp) {  // prefetch next tile; hides under compute
            av = *(const uint4*)(Ap + k0 + 16);
            bv = *(const uint4*)(Bp + k0 + 16);
        }
#pragma unroll
        for (int kk = 0; kk < 16; ++kk) {
            unsigned a[4], b[4];
            *(uint4*)a = *(const uint4*)&As[kk][ty * 4];
            *(uint4*)b = *(const uint4*)&Bs[kk][tx * 4];
#pragma unroll
            for (int i = 0; i < 4; ++i)
#pragma unroll
                for (int j = 0; j < 4; ++j) acc[i][j] = dot2(a[i], b[j], acc[i][j]);
        }
    }
    float bb[4];
#pragma unroll
    for (int j = 0; j < 4; ++j) {
        float v = bias[n0 + tx * 4 + j];
        if (bias2) v += bias2[n0 + tx * 4 + j];
        bb[j] = v;
    }
#pragma unroll
    for (int i = 0; i < 4; ++i) {
        float4 o;
        o.x = acc[i][0] + bb[0];
        o.y = acc[i][1] + bb[1];
        o.z = acc[i][2] + bb[2];
        o.w = acc[i][3] + bb[3];
        if (relu) {
            o.x = fmaxf(o.x, 0.0f);
            o.y = fmaxf(o.y, 0.0f);
            o.z = fmaxf(o.z, 0.0f);
            o.w = fmaxf(o.w, 0.0f);
        }
        size_t mrow = (size_t)(m0 + ty * 4 + i);
        if (C) *(float4*)&C[mrow * N + n0 + tx * 4] = o;
        if (Ch) {
            unsigned* cp = Ch + mrow * (N >> 1) + (n0 >> 1) + tx * 2;
            cp[0] = pack2_rne(o.x, o.y);
            cp[1] = pack2_rne(o.z, o.w);
        }
    }
}

// ---- LSTM R15 (unchanged): R13 structure + done-mask skip ------------------
__global__ __launch_bounds__(1024) void lstm_kernel(const float* __restrict__ gi,
                                                    const unsigned* __restrict__ wp,
                                                    const int* __restrict__ done,
                                                    const float* __restrict__ h0,
                                                    const float* __restrict__ c0,
                                                    float* __restrict__ out) {
    __shared__ alignas(16) unsigned wo[32768];  // o-rows f16x2: [d4][256][4], 128 KB
    __shared__ alignas(16) unsigned h2u[128];   // h as f16x2, 512 B
    __shared__ float xch[4096];                 // partials [q][gate][u], 16 KB
    int b = blockIdx.x, tt = threadIdx.x;
    int u = tt & 255, q = tt >> 8;
    int q8 = q * 8;

    const uint4* wsrc = (const uint4*)wp;

    // stage o-rows (768..1023) into LDS: wo4[d4*256 + r] = wp4[d4*1024 + 768 + r]
    {
        uint4* dst = (uint4*)wo;
        for (int i4 = tt; i4 < 8192; i4 += 1024) {
            int d4 = i4 >> 8, r = i4 & 255;
            dst[i4] = wsrc[d4 * 1024 + 768 + r];
        }
    }

    // 24 named register weights: k-octets q8..q8+7 of rows u / 256+u / 512+u
    // (compiler remats these into the loop; with the dn-branch they only
    // issue on unmasked steps)
#define LDW(j)                                              \
    uint4 wi##j = wsrc[(q8 + j) * 1024 + u];                \
    uint4 wf##j = wsrc[(q8 + j) * 1024 + 256 + u];          \
    uint4 wg##j = wsrc[(q8 + j) * 1024 + 512 + u];
    LDW(0) LDW(1) LDW(2) LDW(3) LDW(4) LDW(5) LDW(6) LDW(7)
#undef LDW

    // init h (packed f16x2) and per-unit state
    if (tt < 128) {
        h2u[tt] = pack2_rne(h0[b * 256 + 2 * tt], h0[b * 256 + 2 * tt + 1]);
    }
    float c = 0.0f;
    float gv0 = 0.f, gv1 = 0.f, gv2 = 0.f, gv3 = 0.f;
    int dn = done[b];  // ALL threads track dn (block-uniform)
    const float* gbase = gi + (size_t)b * 1024;  // step stride 32*1024 floats
    if (q == 0) {
        c = c0[b * 256 + u];
        gv0 = gbase[u];
        gv1 = gbase[256 + u];
        gv2 = gbase[512 + u];
        gv3 = gbase[768 + u];
    }
    __syncthreads();

    const uint4* h2u4 = (const uint4*)h2u;
    const uint4* wo4 = (const uint4*)wo;

    for (int step = 0; step < 64; ++step) {
        // prefetch next step's done (all threads, uniform) + gate inputs (q==0)
        int dnn = 0;
        if (step < 63) dnn = done[(step + 1) * 32 + b];
        float nx0 = 0.f, nx1 = 0.f, nx2 = 0.f, nx3 = 0.f;
        if (q == 0 && step < 63) {
            const float* gb = gbase + (size_t)(step + 1) * 32768;
            nx0 = gb[u];
            nx1 = gb[256 + u];
            nx2 = gb[512 + u];
            nx3 = gb[768 + u];
        }

        float pI = 0.f, pF = 0.f, pG = 0.f, pO = 0.f;
        if (!dn) {  // m==1: recurrent term live -> do the matvec
#define MV(j) {                                                         \
        uint4 ha = h2u4[q8 + j];      /* broadcast (uniform addr) */    \
        uint4 wv = wo4[(q8 + j) * 256 + u]; /* o row, conflict-free */  \
        pI = dot2(ha.x, wi##j.x, pI); pI = dot2(ha.y, wi##j.y, pI);     \
        pI = dot2(ha.z, wi##j.z, pI); pI = dot2(ha.w, wi##j.w, pI);     \
        pF = dot2(ha.x, wf##j.x, pF); pF = dot2(ha.y, wf##j.y, pF);     \
        pF = dot2(ha.z, wf##j.z, pF); pF = dot2(ha.w, wf##j.w, pF);     \
        pG = dot2(ha.x, wg##j.x, pG); pG = dot2(ha.y, wg##j.y, pG);     \
        pG = dot2(ha.z, wg##j.z, pG); pG = dot2(ha.w, wg##j.w, pG);     \
        pO = dot2(ha.x, wv.x, pO);    pO = dot2(ha.y, wv.y, pO);        \
        pO = dot2(ha.z, wv.z, pO);    pO = dot2(ha.w, wv.w, pO); }
            MV(0) MV(1) MV(2) MV(3) MV(4) MV(5) MV(6) MV(7)
#undef MV
        }

        // post partials: xch[q*1024 + gate*256 + u]
        xch[q * 1024 + u] = pI;
        xch[q * 1024 + 256 + u] = pF;
        xch[q * 1024 + 512 + u] = pG;
        xch[q * 1024 + 768 + u] = pO;
        __syncthreads();  // partials visible; all h2u reads of this step done

        if (q == 0) {
            float m = 1.0f - (float)dn;
            float sI = xch[u] + xch[1024 + u] + xch[2048 + u] + xch[3072 + u];
            float sF = xch[256 + u] + xch[1280 + u] + xch[2304 + u] + xch[3328 + u];
            float sG = xch[512 + u] + xch[1536 + u] + xch[2560 + u] + xch[3584 + u];
            float sO = xch[768 + u] + xch[1792 + u] + xch[2816 + u] + xch[3840 + u];
            float g_i = gv0 + m * sI;
            float g_f = gv1 + m * sF;
            float g_g = gv2 + m * sG;
            float g_o = gv3 + m * sO;
            float si = 1.0f / (1.0f + __expf(-g_i));
            float sf = 1.0f / (1.0f + __expf(-g_f));
            float so = 1.0f / (1.0f + __expf(-g_o));
            float tg = fast_tanh(g_g);
            c = sf * (c * m) + si * tg;
            float hn = so * fast_tanh(c);
            out[((size_t)step * 32 + b) * 256 + u] = hn;
            float hn2 = __shfl_xor(hn, 1);
            if ((u & 1) == 0) {
                unsigned lo = f2h_bits(hn);
                unsigned hi = f2h_bits(hn2);
                h2u[u >> 1] = lo | (hi << 16);
            }
        }
        __syncthreads();  // new h + freed xch visible before next step

        gv0 = nx0; gv1 = nx1; gv2 = nx2; gv3 = nx3;
        dn = dnn;
    }
}

// ---------------------------------------------------------------------------
extern "C" void kernel_launch(void* const* d_in, const int* in_sizes, int n_in,
                              void* d_out, int out_size, void* d_ws, size_t ws_size,
                              hipStream_t stream) {
    const float* x    = (const float*)d_in[0];
    const int*   done = (const int*)d_in[1];
    const float* w1   = (const float*)d_in[2];
    const float* b1   = (const float*)d_in[3];
    const float* w2   = (const float*)d_in[4];
    const float* b2   = (const float*)d_in[5];
    const float* w3   = (const float*)d_in[6];
    const float* b3   = (const float*)d_in[7];
    const float* fcw  = (const float*)d_in[8];
    const float* fcb  = (const float*)d_in[9];
    const float* wih  = (const float*)d_in[10];
    const float* whh  = (const float*)d_in[11];
    const float* bih  = (const float*)d_in[12];
    const float* bhh  = (const float*)d_in[13];
    const float* h0   = (const float*)d_in[14];
    const float* c0   = (const float*)d_in[15];
    float* out = (float*)d_out;
    float* ws = (float*)d_ws;

    // workspace layout (float offsets):
    // z1u (f16): [0, 7,864,320) FLOATS of shorts -- (2048, 32, 15, 16)
    // z2:        [8,000,000, 12,718,592)         (conv2 out, dead after conv3)
    // z3h (uint):[0, 1,048,576)                  (z1u dead after conv2)
    // featsh:    [2,097,152, +524,288) (uint)
    // gi:        [3,145,728, 5,242,880)
    // fcwph:     [8,000,000, +262,144) (uint)    (packed AFTER conv3; z2 dead)
    // wihph:     [8,300,000, +262,144) (uint)
    // w3t:       [13,000,000, +36,864)
    // w1p:       [13,100,000, +4,096)   (uint)
    // w2p:       [13,200,000, +16,384)  (uint)
    // wp (whh packed f16x2, uint[131072]): [13,300,000, 13,431,072)
    //   NOTE: wp MUST live past z1u's end (7,864,320) -- conv1 writes z1u
    //   after the pack kernels run. R9 had it at 5.5M and got clobbered.
    //   NOTE: fcwph/wihph live in z2's region -> their pack kernels MUST
    //   launch after conv3 (the last reader of z2).
    unsigned short* z1u = (unsigned short*)(ws + 0);
    float* z2     = ws + 8000000;
    unsigned* z3h = (unsigned*)(ws + 0);
    unsigned* featsh = (unsigned*)(ws + 2097152);
    float* gi     = ws + 3145728;
    unsigned* fcwph = (unsigned*)(ws + 8000000);
    unsigned* wihph = (unsigned*)(ws + 8300000);
    float* w3t    = ws + 13000000;
    unsigned* w1p = (unsigned*)(ws + 13100000);
    unsigned* w2p = (unsigned*)(ws + 13200000);
    unsigned* wp  = (unsigned*)(ws + 13300000);

    transpose_kernel<<<(64 * 576 + 255) / 256, 256, 0, stream>>>(w3, w3t, 64, 576);
    pack_whh_pairs_kernel<<<512, 256, 0, stream>>>(whh, wp);
    pack_w1_kernel<<<16, 256, 0, stream>>>(w1, w1p);
    pack_w2_kernel<<<64, 256, 0, stream>>>(w2, w2p);

    conv1_kernel<<<NIMG, 1024, 0, stream>>>(x, w1p, b1, z1u);
    conv2_kernel<<<NIMG / 2, 768, 0, stream>>>(z1u, w2p, b2, z2);
    conv3_kernel<<<NIMG / 4, 512, 0, stream>>>(z2, w3t, b3, z3h);

    // pack GEMM weights (after conv3: fcwph/wihph overlay the dead z2)
    pack_pairs_kernel<<<(512 * 512 + 255) / 256, 256, 0, stream>>>(fcw, fcwph, 512 * 512);
    pack_pairs_kernel<<<(1024 * 256 + 255) / 256, 256, 0, stream>>>(wih, wihph, 1024 * 256);

    // gemm1: feats = relu(z3 @ fcw^T + fcb), emitted as f16 pairs only
    gemm_bt_h<<<dim3(512 / 64, NIMG / 64), 256, 0, stream>>>(
        z3h, fcwph, fcb, nullptr, nullptr, featsh, NIMG, 512, 512, 1);
    // gemm2: gi = feats @ wih^T + bih + bhh (fp32 out)
    gemm_bt_h<<<dim3(1024 / 64, NIMG / 64), 256, 0, stream>>>(
        featsh, wihph, bih, bhh, gi, nullptr, NIMG, 1024, 256, 0);

    lstm_kernel<<<32, 1024, 0, stream>>>(gi, wp, done, h0, c0, out);
}

// Round 9
// 520.338 us; speedup vs baseline: 1.7640x; 1.0878x over previous
//
#include <hip/hip_runtime.h>
#include <math.h>

// ---------------------------------------------------------------------------
// RecurrentNatureCNN: conv1(8x8,s4) -> conv2(4x4,s2) -> conv3(3x3,s1) -> FC
//                     -> LSTM(T=64,B=32,H=256)
// N = T*B = 2048 images.
// R17: = R16 (lstm 120us floor kept; f16 GEMMs kept) with:
//      (a) conv3 v2: weights staged in LDS (f16 pairs, 73.7 KB) + 8 images'
//          acts in LDS (f16 [icp][pos], 36.9 KB). Old conv3 streamed 2.36 MB
//          of weights per block from L2 (per-lane addrs, 147 KB > L1);
//          now 110 KB/block (21x less) + dot2 instead of fp32 FMA.
//      (b) conv2 emits z2h f16 [n][pos][ic] directly (shfl-pair, coalesced).
//      (c) 6 prologue pack/transpose kernels merged into one pack_all
//          (launches 11 -> 7).
//      conv1, gemms, LSTM unchanged from R16.
// ---------------------------------------------------------------------------

#define NIMG 2048

typedef _Float16 half2_t __attribute__((ext_vector_type(2)));
typedef __fp16 fp16x2_t __attribute__((ext_vector_type(2)));

__device__ inline unsigned short f2h_bits(float f) {
    union { _Float16 h; unsigned short u; } x;
    x.h = (_Float16)f;
    return x.u;
}

__device__ inline unsigned pack2_rne(float a, float b) {
    return (unsigned)f2h_bits(a) | ((unsigned)f2h_bits(b) << 16);
}

__device__ inline unsigned pack2_fast(float a, float b) {
#if __has_builtin(__builtin_amdgcn_cvt_pkrtz)
    union { fp16x2_t h; unsigned u; } x;
    x.h = __builtin_amdgcn_cvt_pkrtz(a, b);
    return x.u;
#else
    return pack2_rne(a, b);
#endif
}

__device__ inline float dot2(unsigned hu, unsigned wu, float acc) {
    union { unsigned u; half2_t h; } a, b;
    a.u = hu; b.u = wu;
#if __has_builtin(__builtin_amdgcn_fdot2)
    return __builtin_amdgcn_fdot2(a.h, b.h, acc, false);
#else
    return acc + (float)a.h.x * (float)b.h.x + (float)a.h.y * (float)b.h.y;
#endif
}

__device__ inline float fast_tanh(float x) {
    return 1.0f - 2.0f / (__expf(2.0f * x) + 1.0f);
}

// ---- pack_all: every weight prep in ONE kernel -----------------------------
// seg0 whh->wp (131072): f16x2 pairs, uint4-interleaved by row
//      wp4[d4*1024 + row] = row's packed k = [d4*8, d4*8+8)
// seg1 w1->w1p (4096):   pairs along kx
// seg2 w2->w2p (16384):  [(ic*4+ky)*2+kxp][oc]
// seg3 w3->w3ph (18432): [ky][kx][icp][oc], pairs along ic
// seg4 fcw->fcwph (262144): contiguous pair-pack along K
// seg5 wih->wihph (262144): contiguous pair-pack along K
__global__ void pack_all_kernel(const float* __restrict__ whh,
                                const float* __restrict__ w1,
                                const float* __restrict__ w2,
                                const float* __restrict__ w3,
                                const float* __restrict__ fcw,
                                const float* __restrict__ wih,
                                unsigned* __restrict__ wp,
                                unsigned* __restrict__ w1p,
                                unsigned* __restrict__ w2p,
                                unsigned* __restrict__ w3ph,
                                unsigned* __restrict__ fcwph,
                                unsigned* __restrict__ wihph) {
    int idx = blockIdx.x * 256 + threadIdx.x;
    if (idx < 131072) {
        int d4 = idx >> 12, rem = idx & 4095, row = rem >> 2, j = idx & 3;
        const float* s = whh + (size_t)row * 256 + d4 * 8 + j * 2;
        wp[idx] = pack2_rne(s[0], s[1]);
        return;
    }
    idx -= 131072;
    if (idx < 4096) {
        int oc = idx >> 7, rem = idx & 127;
        int ic = rem >> 5, ky = (rem >> 2) & 7, kxp = rem & 3;
        const float* s = w1 + (((size_t)oc * 4 + ic) * 8 + ky) * 8 + kxp * 2;
        w1p[idx] = pack2_rne(s[0], s[1]);
        return;
    }
    idx -= 4096;
    if (idx < 16384) {
        int p = idx >> 6, oc = idx & 63;
        int ic = p >> 3, ky = (p >> 1) & 3, kxp = p & 1;
        const float* s = w2 + (size_t)oc * 512 + ic * 16 + ky * 4 + kxp * 2;
        w2p[idx] = pack2_rne(s[0], s[1]);
        return;
    }
    idx -= 16384;
    if (idx < 18432) {
        int oc = idx & 63, rest = idx >> 6;   // rest = kxy*32 + icp, 0..287
        int icp = rest & 31, kxy = rest >> 5;
        int ky = kxy / 3, kx = kxy - ky * 3;
        const float* s = w3 + (((size_t)oc * 64 + icp * 2) * 3 + ky) * 3 + kx;
        w3ph[idx] = pack2_rne(s[0], s[9]);    // ic stride = 3*3
        return;
    }
    idx -= 18432;
    if (idx < 262144) {
        const float* s = fcw + (size_t)idx * 2;
        fcwph[idx] = pack2_rne(s[0], s[1]);
        return;
    }
    idx -= 262144;
    if (idx < 262144) {
        const float* s = wih + (size_t)idx * 2;
        wihph[idx] = pack2_rne(s[0], s[1]);
    }
}

// ---- conv1: x (n,4,64,64)/255 -> relu -> z1 f16 (n,32,15,16 padded) --------
__global__ __launch_bounds__(1024) void conv1_kernel(const float* __restrict__ x,
                                                     const unsigned* __restrict__ w1p,
                                                     const float* __restrict__ b,
                                                     unsigned short* __restrict__ z1) {
    __shared__ unsigned short xs[4 * 64 * 64];  // f16, 32768 B
    int n = blockIdx.x;
    int tid = threadIdx.x;
    const float* xp = x + (size_t)n * 16384;
    const float inv = 1.0f / 255.0f;
    for (int i = tid * 4; i < 16384; i += 4096) {
        float4 v = *(const float4*)(xp + i);
        uint2 q;
        q.x = pack2_fast(v.x * inv, v.y * inv);
        q.y = pack2_fast(v.z * inv, v.w * inv);
        *(uint2*)&xs[i] = q;
    }
    __syncthreads();
    int lane = tid & 63, wave = tid >> 6;
    int gg = __builtin_amdgcn_readfirstlane(wave & 3);
    int pos = (wave >> 2) * 64 + lane;  // 0..255
    if (pos < 225) {
        int oy = pos / 15, ox = pos - oy * 15;
        float acc[8];
        const float* bp = b + gg * 8;
#pragma unroll
        for (int u = 0; u < 8; ++u) acc[u] = bp[u];
        for (int ic = 0; ic < 4; ++ic) {
#pragma unroll
            for (int ky = 0; ky < 8; ++ky) {
                const unsigned short* row = &xs[(ic * 64 + oy * 4 + ky) * 64 + ox * 4];
                uint2 qa = *(const uint2*)row;        // cols +0..3 (2 pairs)
                uint2 qb = *(const uint2*)(row + 4);  // cols +4..7 (2 pairs)
                const unsigned* wpt = w1p + ((((gg * 8) * 4 + ic) * 8 + ky) * 4);
#pragma unroll
                for (int u = 0; u < 8; ++u) {
                    const unsigned* wu = wpt + u * 128;  // (oc stride 4*8*4)
                    acc[u] = dot2(qa.x, wu[0], acc[u]);
                    acc[u] = dot2(qa.y, wu[1], acc[u]);
                    acc[u] = dot2(qb.x, wu[2], acc[u]);
                    acc[u] = dot2(qb.y, wu[3], acc[u]);
                }
            }
        }
        unsigned short* op = z1 + (size_t)n * 7680 + (gg * 8) * 240 + oy * 16 + ox;
#pragma unroll
        for (int u = 0; u < 8; ++u) op[u * 240] = f2h_bits(fmaxf(acc[u], 0.0f));
    }
}

// ---- conv2: z1 f16 (n,32,15,16) -> relu -> z2h f16 [n][pos(36)][ic(64)] ----
__global__ __launch_bounds__(768) void conv2_kernel(const unsigned short* __restrict__ z1,
                                                    const unsigned* __restrict__ w2p,
                                                    const float* __restrict__ bias,
                                                    unsigned* __restrict__ z2h) {
    __shared__ unsigned short xs[2][32 * 15 * 16];  // f16, 30720 B
    int tid = threadIdx.x;
    int n0 = blockIdx.x * 2;
#pragma unroll
    for (int img = 0; img < 2; ++img) {
        const unsigned* src = (const unsigned*)(z1 + (size_t)(n0 + img) * 7680);
        unsigned* dst = (unsigned*)xs[img];
        for (int i = tid; i < 3840; i += 768) dst[i] = src[i];
    }
    __syncthreads();
    int lane = tid & 63, wave = tid >> 6;  // wave 0..11
    int img = wave / 6;
    int oy = wave - img * 6;
    int n = n0 + img;
    float bv = bias[lane];
    float acc[6];
#pragma unroll
    for (int u = 0; u < 6; ++u) acc[u] = bv;
    for (int ic = 0; ic < 32; ++ic) {
#pragma unroll
        for (int ky = 0; ky < 4; ++ky) {
            const unsigned short* row = &xs[img][(ic * 15 + oy * 2 + ky) * 16];
            uint4 pa = *(const uint4*)row;        // pairs 0..3  (cols 0..7)
            uint4 pb = *(const uint4*)(row + 8);  // pairs 4..7  (cols 8..15)
            unsigned p[8] = {pa.x, pa.y, pa.z, pa.w, pb.x, pb.y, pb.z, pb.w};
            const unsigned* wpp = w2p + ((ic * 4 + ky) * 2) * 64 + lane;
            unsigned wa = wpp[0];   // kx 0,1
            unsigned wb = wpp[64];  // kx 2,3
#pragma unroll
            for (int u = 0; u < 6; ++u) {
                acc[u] = dot2(p[u], wa, acc[u]);
                acc[u] = dot2(p[u + 1], wb, acc[u]);
            }
        }
    }
    // epilogue: f16 pairs along ic. z2h[n*1152 + pos*32 + ic/2]
    unsigned* zb = z2h + (size_t)n * 1152;
#pragma unroll
    for (int u = 0; u < 6; ++u) {
        float a = fmaxf(acc[u], 0.0f);
        float a2 = __shfl_xor(a, 1);
        if ((lane & 1) == 0) {
            zb[(oy * 6 + u) * 32 + (lane >> 1)] = pack2_rne(a, a2);
        }
    }
}

// ---- conv3 v2: z2h f16 -> relu -> z3h f16-pairs (n, 512 uints) -------------
// Block = 8 images, 512 threads (wave=img, lane=oc). ALL weights (73.7 KB,
// f16 pairs) + all 8 images' acts (36.9 KB, transposed to [icp][pos] during
// staging so compute reads are uniform b128 broadcasts) live in LDS.
// Per-block L2 traffic 110 KB (was 2.36 MB with per-lane global wt reads).
__global__ __launch_bounds__(512) void conv3_kernel(const unsigned* __restrict__ z2h,
                                                    const unsigned* __restrict__ w3ph,
                                                    const float* __restrict__ bias,
                                                    unsigned* __restrict__ outp) {
    __shared__ unsigned w3s[18432];    // [kxy(9)][icp(32)][oc(64)], 73728 B
    __shared__ unsigned xs8[8][1152];  // [img][icp(32)][pos(36)], 36864 B
    int tid = threadIdx.x;
    int n0 = blockIdx.x * 8;
    for (int i = tid; i < 18432; i += 512) w3s[i] = w3ph[i];
    for (int i = tid; i < 8 * 1152; i += 512) {
        int img = i / 1152;
        int rem = i - img * 1152;     // src: pos*32 + icp
        int pos = rem >> 5, icp = rem & 31;
        xs8[img][icp * 36 + pos] = z2h[(size_t)(n0 + img) * 1152 + rem];
    }
    __syncthreads();
    int lane = tid & 63, img = tid >> 6;
    int n = n0 + img;
    float bv = bias[lane];
    float acc[4][4];
#pragma unroll
    for (int oy = 0; oy < 4; ++oy)
#pragma unroll
        for (int ox = 0; ox < 4; ++ox) acc[oy][ox] = bv;
    const unsigned* wb = w3s + lane;
    const unsigned* xb = xs8[img];
    for (int icp = 0; icp < 32; ++icp) {
        unsigned xr[36];  // this icp's 6x6 window, uniform-addr broadcast
#pragma unroll
        for (int p4 = 0; p4 < 9; ++p4)
            *(uint4*)&xr[p4 * 4] = *(const uint4*)&xb[icp * 36 + p4 * 4];
#pragma unroll
        for (int ky = 0; ky < 3; ++ky)
#pragma unroll
            for (int kx = 0; kx < 3; ++kx) {
                unsigned w = wb[((ky * 3 + kx) * 32 + icp) * 64];
#pragma unroll
                for (int oy = 0; oy < 4; ++oy)
#pragma unroll
                    for (int ox = 0; ox < 4; ++ox)
                        acc[oy][ox] = dot2(xr[(oy + ky) * 6 + ox + kx], w, acc[oy][ox]);
            }
    }
    // z3 feature = oc*16 + oy*4 + ox; pairs along feature dim
    unsigned* op = outp + (size_t)n * 512 + lane * 8;
#pragma unroll
    for (int oy = 0; oy < 4; ++oy) {
        float a0 = fmaxf(acc[oy][0], 0.f), a1 = fmaxf(acc[oy][1], 0.f);
        float a2 = fmaxf(acc[oy][2], 0.f), a3 = fmaxf(acc[oy][3], 0.f);
        op[oy * 2 + 0] = pack2_rne(a0, a1);
        op[oy * 2 + 1] = pack2_rne(a2, a3);
    }
}

// ---- GEMM f16: C(M,N) = [relu]( A @ B^T + bias [+bias2] ), A/B f16 pairs ---
__global__ __launch_bounds__(256) void gemm_bt_h(const unsigned* __restrict__ A,
                                                 const unsigned* __restrict__ B,
                                                 const float* __restrict__ bias,
                                                 const float* __restrict__ bias2,
                                                 float* __restrict__ C,
                                                 unsigned* __restrict__ Ch,
                                                 int M, int N, int Kp, int relu) {
    __shared__ unsigned As[16][66];
    __shared__ unsigned Bs[16][66];
    int tid = threadIdx.x;
    int m0 = blockIdx.y * 64, n0 = blockIdx.x * 64;
    int tx = tid & 15, ty = tid >> 4;
    int lr = tid >> 2;
    int lk = (tid & 3) * 4;
    const unsigned* Ap = A + (size_t)(m0 + lr) * Kp + lk;
    const unsigned* Bp = B + (size_t)(n0 + lr) * Kp + lk;
    float acc[4][4];
#pragma unroll
    for (int i = 0; i < 4; ++i)
#pragma unroll
        for (int j = 0; j < 4; ++j) acc[i][j] = 0.0f;

    uint4 av = *(const uint4*)Ap;
    uint4 bv = *(const uint4*)Bp;
    for (int k0 = 0; k0 < Kp; k0 += 16) {
        __syncthreads();
        As[lk + 0][lr] = av.x;
        As[lk + 1][lr] = av.y;
        As[lk + 2][lr] = av.z;
        As[lk + 3][lr] = av.w;
        Bs[lk + 0][lr] = bv.x;
        Bs[lk + 1][lr] = bv.y;
        Bs[lk + 2][lr] = bv.z;
        Bs[lk + 3][lr] = bv.w;
        __syncthreads();
        if (k0 + 16 < Kp) {  // prefetch next tile; hides under compute
            av = *(const uint4*)(Ap + k0 + 16);
            bv = *(const uint4*)(Bp + k0 + 16);
        }
#pragma unroll
        for (int kk = 0; kk < 16; ++kk) {
            unsigned a[4], b[4];
            *(uint4*)a = *(const uint4*)&As[kk][ty * 4];
            *(uint4*)b = *(const uint4*)&Bs[kk][tx * 4];
#pragma unroll
            for (int i = 0; i < 4; ++i)
#pragma unroll
                for (int j = 0; j < 4; ++j) acc[i][j] = dot2(a[i], b[j], acc[i][j]);
        }
    }
    float bb[4];
#pragma unroll
    for (int j = 0; j < 4; ++j) {
        float v = bias[n0 + tx * 4 + j];
        if (bias2) v += bias2[n0 + tx * 4 + j];
        bb[j] = v;
    }
#pragma unroll
    for (int i = 0; i < 4; ++i) {
        float4 o;
        o.x = acc[i][0] + bb[0];
        o.y = acc[i][1] + bb[1];
        o.z = acc[i][2] + bb[2];
        o.w = acc[i][3] + bb[3];
        if (relu) {
            o.x = fmaxf(o.x, 0.0f);
            o.y = fmaxf(o.y, 0.0f);
            o.z = fmaxf(o.z, 0.0f);
            o.w = fmaxf(o.w, 0.0f);
        }
        size_t mrow = (size_t)(m0 + ty * 4 + i);
        if (C) *(float4*)&C[mrow * N + n0 + tx * 4] = o;
        if (Ch) {
            unsigned* cp = Ch + mrow * (N >> 1) + (n0 >> 1) + tx * 2;
            cp[0] = pack2_rne(o.x, o.y);
            cp[1] = pack2_rne(o.z, o.w);
        }
    }
}

// ---- LSTM (unchanged from R15): R13 structure + done-mask skip -------------
__global__ __launch_bounds__(1024) void lstm_kernel(const float* __restrict__ gi,
                                                    const unsigned* __restrict__ wp,
                                                    const int* __restrict__ done,
                                                    const float* __restrict__ h0,
                                                    const float* __restrict__ c0,
                                                    float* __restrict__ out) {
    __shared__ alignas(16) unsigned wo[32768];  // o-rows f16x2: [d4][256][4], 128 KB
    __shared__ alignas(16) unsigned h2u[128];   // h as f16x2, 512 B
    __shared__ float xch[4096];                 // partials [q][gate][u], 16 KB
    int b = blockIdx.x, tt = threadIdx.x;
    int u = tt & 255, q = tt >> 8;
    int q8 = q * 8;

    const uint4* wsrc = (const uint4*)wp;

    // stage o-rows (768..1023) into LDS: wo4[d4*256 + r] = wp4[d4*1024 + 768 + r]
    {
        uint4* dst = (uint4*)wo;
        for (int i4 = tt; i4 < 8192; i4 += 1024) {
            int d4 = i4 >> 8, r = i4 & 255;
            dst[i4] = wsrc[d4 * 1024 + 768 + r];
        }
    }

    // 24 named register weights: k-octets q8..q8+7 of rows u / 256+u / 512+u
    // (compiler remats these into the loop; with the dn-branch they only
    // issue on unmasked steps)
#define LDW(j)                                              \
    uint4 wi##j = wsrc[(q8 + j) * 1024 + u];                \
    uint4 wf##j = wsrc[(q8 + j) * 1024 + 256 + u];          \
    uint4 wg##j = wsrc[(q8 + j) * 1024 + 512 + u];
    LDW(0) LDW(1) LDW(2) LDW(3) LDW(4) LDW(5) LDW(6) LDW(7)
#undef LDW

    // init h (packed f16x2) and per-unit state
    if (tt < 128) {
        h2u[tt] = pack2_rne(h0[b * 256 + 2 * tt], h0[b * 256 + 2 * tt + 1]);
    }
    float c = 0.0f;
    float gv0 = 0.f, gv1 = 0.f, gv2 = 0.f, gv3 = 0.f;
    int dn = done[b];  // ALL threads track dn (block-uniform)
    const float* gbase = gi + (size_t)b * 1024;  // step stride 32*1024 floats
    if (q == 0) {
        c = c0[b * 256 + u];
        gv0 = gbase[u];
        gv1 = gbase[256 + u];
        gv2 = gbase[512 + u];
        gv3 = gbase[768 + u];
    }
    __syncthreads();

    const uint4* h2u4 = (const uint4*)h2u;
    const uint4* wo4 = (const uint4*)wo;

    for (int step = 0; step < 64; ++step) {
        // prefetch next step's done (all threads, uniform) + gate inputs (q==0)
        int dnn = 0;
        if (step < 63) dnn = done[(step + 1) * 32 + b];
        float nx0 = 0.f, nx1 = 0.f, nx2 = 0.f, nx3 = 0.f;
        if (q == 0 && step < 63) {
            const float* gb = gbase + (size_t)(step + 1) * 32768;
            nx0 = gb[u];
            nx1 = gb[256 + u];
            nx2 = gb[512 + u];
            nx3 = gb[768 + u];
        }

        float pI = 0.f, pF = 0.f, pG = 0.f, pO = 0.f;
        if (!dn) {  // m==1: recurrent term live -> do the matvec
#define MV(j) {                                                         \
        uint4 ha = h2u4[q8 + j];      /* broadcast (uniform addr) */    \
        uint4 wv = wo4[(q8 + j) * 256 + u]; /* o row, conflict-free */  \
        pI = dot2(ha.x, wi##j.x, pI); pI = dot2(ha.y, wi##j.y, pI);     \
        pI = dot2(ha.z, wi##j.z, pI); pI = dot2(ha.w, wi##j.w, pI);     \
        pF = dot2(ha.x, wf##j.x, pF); pF = dot2(ha.y, wf##j.y, pF);     \
        pF = dot2(ha.z, wf##j.z, pF); pF = dot2(ha.w, wf##j.w, pF);     \
        pG = dot2(ha.x, wg##j.x, pG); pG = dot2(ha.y, wg##j.y, pG);     \
        pG = dot2(ha.z, wg##j.z, pG); pG = dot2(ha.w, wg##j.w, pG);     \
        pO = dot2(ha.x, wv.x, pO);    pO = dot2(ha.y, wv.y, pO);        \
        pO = dot2(ha.z, wv.z, pO);    pO = dot2(ha.w, wv.w, pO); }
            MV(0) MV(1) MV(2) MV(3) MV(4) MV(5) MV(6) MV(7)
#undef MV
        }

        // post partials: xch[q*1024 + gate*256 + u]
        xch[q * 1024 + u] = pI;
        xch[q * 1024 + 256 + u] = pF;
        xch[q * 1024 + 512 + u] = pG;
        xch[q * 1024 + 768 + u] = pO;
        __syncthreads();  // partials visible; all h2u reads of this step done

        if (q == 0) {
            float m = 1.0f - (float)dn;
            float sI = xch[u] + xch[1024 + u] + xch[2048 + u] + xch[3072 + u];
            float sF = xch[256 + u] + xch[1280 + u] + xch[2304 + u] + xch[3328 + u];
            float sG = xch[512 + u] + xch[1536 + u] + xch[2560 + u] + xch[3584 + u];
            float sO = xch[768 + u] + xch[1792 + u] + xch[2816 + u] + xch[3840 + u];
            float g_i = gv0 + m * sI;
            float g_f = gv1 + m * sF;
            float g_g = gv2 + m * sG;
            float g_o = gv3 + m * sO;
            float si = 1.0f / (1.0f + __expf(-g_i));
            float sf = 1.0f / (1.0f + __expf(-g_f));
            float so = 1.0f / (1.0f + __expf(-g_o));
            float tg = fast_tanh(g_g);
            c = sf * (c * m) + si * tg;
            float hn = so * fast_tanh(c);
            out[((size_t)step * 32 + b) * 256 + u] = hn;
            float hn2 = __shfl_xor(hn, 1);
            if ((u & 1) == 0) {
                unsigned lo = f2h_bits(hn);
                unsigned hi = f2h_bits(hn2);
                h2u[u >> 1] = lo | (hi << 16);
            }
        }
        __syncthreads();  // new h + freed xch visible before next step

        gv0 = nx0; gv1 = nx1; gv2 = nx2; gv3 = nx3;
        dn = dnn;
    }
}

// ---------------------------------------------------------------------------
extern "C" void kernel_launch(void* const* d_in, const int* in_sizes, int n_in,
                              void* d_out, int out_size, void* d_ws, size_t ws_size,
                              hipStream_t stream) {
    const float* x    = (const float*)d_in[0];
    const int*   done = (const int*)d_in[1];
    const float* w1   = (const float*)d_in[2];
    const float* b1   = (const float*)d_in[3];
    const float* w2   = (const float*)d_in[4];
    const float* b2   = (const float*)d_in[5];
    const float* w3   = (const float*)d_in[6];
    const float* b3   = (const float*)d_in[7];
    const float* fcw  = (const float*)d_in[8];
    const float* fcb  = (const float*)d_in[9];
    const float* wih  = (const float*)d_in[10];
    const float* whh  = (const float*)d_in[11];
    const float* bih  = (const float*)d_in[12];
    const float* bhh  = (const float*)d_in[13];
    const float* h0   = (const float*)d_in[14];
    const float* c0   = (const float*)d_in[15];
    float* out = (float*)d_out;
    float* ws = (float*)d_ws;

    // workspace layout (float offsets):
    // z1u (f16): [0, 7,864,320) FLOATS of shorts -- (2048, 32, 15, 16)
    // z2h (uint):[8,000,000, 10,359,296)  -- (2048, 36, 32) pairs
    // z3h (uint):[0, 1,048,576)           (z1u dead after conv2)
    // featsh:    [2,097,152, +524,288) (uint)
    // gi:        [3,145,728, 5,242,880)
    // fcwph:     [10,400,000, +262,144) (uint)
    // wihph:     [10,700,000, +262,144) (uint)
    // w3ph:      [13,000,000, +18,432)  (uint)
    // w1p:       [13,100,000, +4,096)   (uint)
    // w2p:       [13,200,000, +16,384)  (uint)
    // wp (whh packed f16x2, uint[131072]): [13,300,000, 13,431,072)
    //   NOTE: all packed-weight regions live past z1u's end (7,864,320) and
    //   outside z2h -- conv1/conv2 write those after pack_all runs.
    unsigned short* z1u = (unsigned short*)(ws + 0);
    unsigned* z2h = (unsigned*)(ws + 8000000);
    unsigned* z3h = (unsigned*)(ws + 0);
    unsigned* featsh = (unsigned*)(ws + 2097152);
    float* gi     = ws + 3145728;
    unsigned* fcwph = (unsigned*)(ws + 10400000);
    unsigned* wihph = (unsigned*)(ws + 10700000);
    unsigned* w3ph  = (unsigned*)(ws + 13000000);
    unsigned* w1p = (unsigned*)(ws + 13100000);
    unsigned* w2p = (unsigned*)(ws + 13200000);
    unsigned* wp  = (unsigned*)(ws + 13300000);

    // one merged pack kernel: 131072+4096+16384+18432+262144+262144 = 694272
    pack_all_kernel<<<(694272 + 255) / 256, 256, 0, stream>>>(
        whh, w1, w2, w3, fcw, wih, wp, w1p, w2p, w3ph, fcwph, wihph);

    conv1_kernel<<<NIMG, 1024, 0, stream>>>(x, w1p, b1, z1u);
    conv2_kernel<<<NIMG / 2, 768, 0, stream>>>(z1u, w2p, b2, z2h);
    conv3_kernel<<<NIMG / 8, 512, 0, stream>>>(z2h, w3ph, b3, z3h);

    // gemm1: feats = relu(z3 @ fcw^T + fcb), emitted as f16 pairs only
    gemm_bt_h<<<dim3(512 / 64, NIMG / 64), 256, 0, stream>>>(
        z3h, fcwph, fcb, nullptr, nullptr, featsh, NIMG, 512, 512, 1);
    // gemm2: gi = feats @ wih^T + bih + bhh (fp32 out)
    gemm_bt_h<<<dim3(1024 / 64, NIMG / 64), 256, 0, stream>>>(
        featsh, wihph, bih, bhh, gi, nullptr, NIMG, 1024, 256, 0);

    lstm_kernel<<<32, 1024, 0, stream>>>(gi, wp, done, h0, c0, out);
}

// Round 10
// 508.063 us; speedup vs baseline: 1.8066x; 1.0242x over previous
//
#include <hip/hip_runtime.h>
#include <math.h>

// ---------------------------------------------------------------------------
// RecurrentNatureCNN: conv1(8x8,s4) -> conv2(4x4,s2) -> conv3(3x3,s1) -> FC
//                     -> LSTM(T=64,B=32,H=256)
// N = T*B = 2048 images.
// R18: = R17 + LDS/L2 latency-batching in the conv inner loops. Theory: the
//      read->use interleave (1-2 loads feeding each dot2 burst) exposes
//      ~120cyc LDS / ~200cyc L2 latency per (ic,ky) step; at 2-4 waves/SIMD
//      TLP doesn't cover it -> the ~3x gap between issue-model (~110us) and
//      measured (~400us) non-lstm time. Fix: hoist ALL of an ic-iteration's
//      loads (conv1: 16 b64; conv2: 8 b128 + 8 L2 weight dwords; conv3:
//      9 LDS weight dwords) ahead of the dot2 burst -> 8-16 outstanding
//      loads amortize the latency. Pure reorder, identical math.
//      Everything else unchanged from R17.
// ---------------------------------------------------------------------------

#define NIMG 2048

typedef _Float16 half2_t __attribute__((ext_vector_type(2)));
typedef __fp16 fp16x2_t __attribute__((ext_vector_type(2)));

__device__ inline unsigned short f2h_bits(float f) {
    union { _Float16 h; unsigned short u; } x;
    x.h = (_Float16)f;
    return x.u;
}

__device__ inline unsigned pack2_rne(float a, float b) {
    return (unsigned)f2h_bits(a) | ((unsigned)f2h_bits(b) << 16);
}

__device__ inline unsigned pack2_fast(float a, float b) {
#if __has_builtin(__builtin_amdgcn_cvt_pkrtz)
    union { fp16x2_t h; unsigned u; } x;
    x.h = __builtin_amdgcn_cvt_pkrtz(a, b);
    return x.u;
#else
    return pack2_rne(a, b);
#endif
}

__device__ inline float dot2(unsigned hu, unsigned wu, float acc) {
    union { unsigned u; half2_t h; } a, b;
    a.u = hu; b.u = wu;
#if __has_builtin(__builtin_amdgcn_fdot2)
    return __builtin_amdgcn_fdot2(a.h, b.h, acc, false);
#else
    return acc + (float)a.h.x * (float)b.h.x + (float)a.h.y * (float)b.h.y;
#endif
}

__device__ inline float fast_tanh(float x) {
    return 1.0f - 2.0f / (__expf(2.0f * x) + 1.0f);
}

// ---- pack_all: every weight prep in ONE kernel -----------------------------
__global__ void pack_all_kernel(const float* __restrict__ whh,
                                const float* __restrict__ w1,
                                const float* __restrict__ w2,
                                const float* __restrict__ w3,
                                const float* __restrict__ fcw,
                                const float* __restrict__ wih,
                                unsigned* __restrict__ wp,
                                unsigned* __restrict__ w1p,
                                unsigned* __restrict__ w2p,
                                unsigned* __restrict__ w3ph,
                                unsigned* __restrict__ fcwph,
                                unsigned* __restrict__ wihph) {
    int idx = blockIdx.x * 256 + threadIdx.x;
    if (idx < 131072) {
        int d4 = idx >> 12, rem = idx & 4095, row = rem >> 2, j = idx & 3;
        const float* s = whh + (size_t)row * 256 + d4 * 8 + j * 2;
        wp[idx] = pack2_rne(s[0], s[1]);
        return;
    }
    idx -= 131072;
    if (idx < 4096) {
        int oc = idx >> 7, rem = idx & 127;
        int ic = rem >> 5, ky = (rem >> 2) & 7, kxp = rem & 3;
        const float* s = w1 + (((size_t)oc * 4 + ic) * 8 + ky) * 8 + kxp * 2;
        w1p[idx] = pack2_rne(s[0], s[1]);
        return;
    }
    idx -= 4096;
    if (idx < 16384) {
        int p = idx >> 6, oc = idx & 63;
        int ic = p >> 3, ky = (p >> 1) & 3, kxp = p & 1;
        const float* s = w2 + (size_t)oc * 512 + ic * 16 + ky * 4 + kxp * 2;
        w2p[idx] = pack2_rne(s[0], s[1]);
        return;
    }
    idx -= 16384;
    if (idx < 18432) {
        int oc = idx & 63, rest = idx >> 6;   // rest = kxy*32 + icp, 0..287
        int icp = rest & 31, kxy = rest >> 5;
        int ky = kxy / 3, kx = kxy - ky * 3;
        const float* s = w3 + (((size_t)oc * 64 + icp * 2) * 3 + ky) * 3 + kx;
        w3ph[idx] = pack2_rne(s[0], s[9]);    // ic stride = 3*3
        return;
    }
    idx -= 18432;
    if (idx < 262144) {
        const float* s = fcw + (size_t)idx * 2;
        fcwph[idx] = pack2_rne(s[0], s[1]);
        return;
    }
    idx -= 262144;
    if (idx < 262144) {
        const float* s = wih + (size_t)idx * 2;
        wihph[idx] = pack2_rne(s[0], s[1]);
    }
}

// ---- conv1: x (n,4,64,64)/255 -> relu -> z1 f16 (n,32,15,16 padded) --------
// R18: per-ic batched LDS loads (16 b64 outstanding) before the 256-dot2 burst.
__global__ __launch_bounds__(1024) void conv1_kernel(const float* __restrict__ x,
                                                     const unsigned* __restrict__ w1p,
                                                     const float* __restrict__ b,
                                                     unsigned short* __restrict__ z1) {
    __shared__ unsigned short xs[4 * 64 * 64];  // f16, 32768 B
    int n = blockIdx.x;
    int tid = threadIdx.x;
    const float* xp = x + (size_t)n * 16384;
    const float inv = 1.0f / 255.0f;
    for (int i = tid * 4; i < 16384; i += 4096) {
        float4 v = *(const float4*)(xp + i);
        uint2 q;
        q.x = pack2_fast(v.x * inv, v.y * inv);
        q.y = pack2_fast(v.z * inv, v.w * inv);
        *(uint2*)&xs[i] = q;
    }
    __syncthreads();
    int lane = tid & 63, wave = tid >> 6;
    int gg = __builtin_amdgcn_readfirstlane(wave & 3);
    int pos = (wave >> 2) * 64 + lane;  // 0..255
    if (pos < 225) {
        int oy = pos / 15, ox = pos - oy * 15;
        float acc[8];
        const float* bp = b + gg * 8;
#pragma unroll
        for (int u = 0; u < 8; ++u) acc[u] = bp[u];
        for (int ic = 0; ic < 4; ++ic) {
            // batch ALL this ic's LDS reads (16 x b64 outstanding)
            uint2 qa[8], qb[8];
#pragma unroll
            for (int ky = 0; ky < 8; ++ky) {
                const unsigned short* row = &xs[(ic * 64 + oy * 4 + ky) * 64 + ox * 4];
                qa[ky] = *(const uint2*)row;        // cols +0..3 (2 pairs)
                qb[ky] = *(const uint2*)(row + 4);  // cols +4..7 (2 pairs)
            }
#pragma unroll
            for (int ky = 0; ky < 8; ++ky) {
                const unsigned* wpt = w1p + ((((gg * 8) * 4 + ic) * 8 + ky) * 4);
#pragma unroll
                for (int u = 0; u < 8; ++u) {
                    const unsigned* wu = wpt + u * 128;  // (oc stride 4*8*4)
                    acc[u] = dot2(qa[ky].x, wu[0], acc[u]);
                    acc[u] = dot2(qa[ky].y, wu[1], acc[u]);
                    acc[u] = dot2(qb[ky].x, wu[2], acc[u]);
                    acc[u] = dot2(qb[ky].y, wu[3], acc[u]);
                }
            }
        }
        unsigned short* op = z1 + (size_t)n * 7680 + (gg * 8) * 240 + oy * 16 + ox;
#pragma unroll
        for (int u = 0; u < 8; ++u) op[u * 240] = f2h_bits(fmaxf(acc[u], 0.0f));
    }
}

// ---- conv2: z1 f16 (n,32,15,16) -> relu -> z2h f16 [n][pos(36)][ic(64)] ----
// R18: per-ic batched loads: 8 b128 LDS + 8 per-lane L2 weight dwords.
__global__ __launch_bounds__(768) void conv2_kernel(const unsigned short* __restrict__ z1,
                                                    const unsigned* __restrict__ w2p,
                                                    const float* __restrict__ bias,
                                                    unsigned* __restrict__ z2h) {
    __shared__ unsigned short xs[2][32 * 15 * 16];  // f16, 30720 B
    int tid = threadIdx.x;
    int n0 = blockIdx.x * 2;
#pragma unroll
    for (int img = 0; img < 2; ++img) {
        const unsigned* src = (const unsigned*)(z1 + (size_t)(n0 + img) * 7680);
        unsigned* dst = (unsigned*)xs[img];
        for (int i = tid; i < 3840; i += 768) dst[i] = src[i];
    }
    __syncthreads();
    int lane = tid & 63, wave = tid >> 6;  // wave 0..11
    int img = wave / 6;
    int oy = wave - img * 6;
    int n = n0 + img;
    float bv = bias[lane];
    float acc[6];
#pragma unroll
    for (int u = 0; u < 6; ++u) acc[u] = bv;
    for (int ic = 0; ic < 32; ++ic) {
        // batch this ic's loads: 8 b128 LDS rows + 8 weight dwords (L2)
        uint4 ra[4], rb[4];
        unsigned wa[4], wb[4];
#pragma unroll
        for (int ky = 0; ky < 4; ++ky) {
            const unsigned short* row = &xs[img][(ic * 15 + oy * 2 + ky) * 16];
            ra[ky] = *(const uint4*)row;        // pairs 0..3  (cols 0..7)
            rb[ky] = *(const uint4*)(row + 8);  // pairs 4..7  (cols 8..15)
            const unsigned* wpp = w2p + ((ic * 4 + ky) * 2) * 64 + lane;
            wa[ky] = wpp[0];   // kx 0,1
            wb[ky] = wpp[64];  // kx 2,3
        }
#pragma unroll
        for (int ky = 0; ky < 4; ++ky) {
            unsigned p[8] = {ra[ky].x, ra[ky].y, ra[ky].z, ra[ky].w,
                             rb[ky].x, rb[ky].y, rb[ky].z, rb[ky].w};
#pragma unroll
            for (int u = 0; u < 6; ++u) {
                acc[u] = dot2(p[u], wa[ky], acc[u]);
                acc[u] = dot2(p[u + 1], wb[ky], acc[u]);
            }
        }
    }
    // epilogue: f16 pairs along ic. z2h[n*1152 + pos*32 + ic/2]
    unsigned* zb = z2h + (size_t)n * 1152;
#pragma unroll
    for (int u = 0; u < 6; ++u) {
        float a = fmaxf(acc[u], 0.0f);
        float a2 = __shfl_xor(a, 1);
        if ((lane & 1) == 0) {
            zb[(oy * 6 + u) * 32 + (lane >> 1)] = pack2_rne(a, a2);
        }
    }
}

// ---- conv3 v2: z2h f16 -> relu -> z3h f16-pairs (n, 512 uints) -------------
// R18: per-icp batched weight loads (9 LDS dwords) before the 144-dot2 burst.
__global__ __launch_bounds__(512) void conv3_kernel(const unsigned* __restrict__ z2h,
                                                    const unsigned* __restrict__ w3ph,
                                                    const float* __restrict__ bias,
                                                    unsigned* __restrict__ outp) {
    __shared__ unsigned w3s[18432];    // [kxy(9)][icp(32)][oc(64)], 73728 B
    __shared__ unsigned xs8[8][1152];  // [img][icp(32)][pos(36)], 36864 B
    int tid = threadIdx.x;
    int n0 = blockIdx.x * 8;
    for (int i = tid; i < 18432; i += 512) w3s[i] = w3ph[i];
    for (int i = tid; i < 8 * 1152; i += 512) {
        int img = i / 1152;
        int rem = i - img * 1152;     // src: pos*32 + icp
        int pos = rem >> 5, icp = rem & 31;
        xs8[img][icp * 36 + pos] = z2h[(size_t)(n0 + img) * 1152 + rem];
    }
    __syncthreads();
    int lane = tid & 63, img = tid >> 6;
    int n = n0 + img;
    float bv = bias[lane];
    float acc[4][4];
#pragma unroll
    for (int oy = 0; oy < 4; ++oy)
#pragma unroll
        for (int ox = 0; ox < 4; ++ox) acc[oy][ox] = bv;
    const unsigned* wb = w3s + lane;
    const unsigned* xb = xs8[img];
    for (int icp = 0; icp < 32; ++icp) {
        unsigned xr[36];  // this icp's 6x6 window, uniform-addr broadcast
#pragma unroll
        for (int p4 = 0; p4 < 9; ++p4)
            *(uint4*)&xr[p4 * 4] = *(const uint4*)&xb[icp * 36 + p4 * 4];
        unsigned wv[9];   // batch the 9 weight reads too
#pragma unroll
        for (int k9 = 0; k9 < 9; ++k9)
            wv[k9] = wb[(k9 * 32 + icp) * 64];
#pragma unroll
        for (int ky = 0; ky < 3; ++ky)
#pragma unroll
            for (int kx = 0; kx < 3; ++kx) {
                unsigned w = wv[ky * 3 + kx];
#pragma unroll
                for (int oy = 0; oy < 4; ++oy)
#pragma unroll
                    for (int ox = 0; ox < 4; ++ox)
                        acc[oy][ox] = dot2(xr[(oy + ky) * 6 + ox + kx], w, acc[oy][ox]);
            }
    }
    // z3 feature = oc*16 + oy*4 + ox; pairs along feature dim
    unsigned* op = outp + (size_t)n * 512 + lane * 8;
#pragma unroll
    for (int oy = 0; oy < 4; ++oy) {
        float a0 = fmaxf(acc[oy][0], 0.f), a1 = fmaxf(acc[oy][1], 0.f);
        float a2 = fmaxf(acc[oy][2], 0.f), a3 = fmaxf(acc[oy][3], 0.f);
        op[oy * 2 + 0] = pack2_rne(a0, a1);
        op[oy * 2 + 1] = pack2_rne(a2, a3);
    }
}

// ---- GEMM f16: C(M,N) = [relu]( A @ B^T + bias [+bias2] ), A/B f16 pairs ---
__global__ __launch_bounds__(256) void gemm_bt_h(const unsigned* __restrict__ A,
                                                 const unsigned* __restrict__ B,
                                                 const float* __restrict__ bias,
                                                 const float* __restrict__ bias2,
                                                 float* __restrict__ C,
                                                 unsigned* __restrict__ Ch,
                                                 int M, int N, int Kp, int relu) {
    __shared__ unsigned As[16][66];
    __shared__ unsigned Bs[16][66];
    int tid = threadIdx.x;
    int m0 = blockIdx.y * 64, n0 = blockIdx.x * 64;
    int tx = tid & 15, ty = tid >> 4;
    int lr = tid >> 2;
    int lk = (tid & 3) * 4;
    const unsigned* Ap = A + (size_t)(m0 + lr) * Kp + lk;
    const unsigned* Bp = B + (size_t)(n0 + lr) * Kp + lk;
    float acc[4][4];
#pragma unroll
    for (int i = 0; i < 4; ++i)
#pragma unroll
        for (int j = 0; j < 4; ++j) acc[i][j] = 0.0f;

    uint4 av = *(const uint4*)Ap;
    uint4 bv = *(const uint4*)Bp;
    for (int k0 = 0; k0 < Kp; k0 += 16) {
        __syncthreads();
        As[lk + 0][lr] = av.x;
        As[lk + 1][lr] = av.y;
        As[lk + 2][lr] = av.z;
        As[lk + 3][lr] = av.w;
        Bs[lk + 0][lr] = bv.x;
        Bs[lk + 1][lr] = bv.y;
        Bs[lk + 2][lr] = bv.z;
        Bs[lk + 3][lr] = bv.w;
        __syncthreads();
        if (k0 + 16 < Kp) {  // prefetch next tile; hides under compute
            av = *(const uint4*)(Ap + k0 + 16);
            bv = *(const uint4*)(Bp + k0 + 16);
        }
#pragma unroll
        for (int kk = 0; kk < 16; ++kk) {
            unsigned a[4], b[4];
            *(uint4*)a = *(const uint4*)&As[kk][ty * 4];
            *(uint4*)b = *(const uint4*)&Bs[kk][tx * 4];
#pragma unroll
            for (int i = 0; i < 4; ++i)
#pragma unroll
                for (int j = 0; j < 4; ++j) acc[i][j] = dot2(a[i], b[j], acc[i][j]);
        }
    }
    float bb[4];
#pragma unroll
    for (int j = 0; j < 4; ++j) {
        float v = bias[n0 + tx * 4 + j];
        if (bias2) v += bias2[n0 + tx * 4 + j];
        bb[j] = v;
    }
#pragma unroll
    for (int i = 0; i < 4; ++i) {
        float4 o;
        o.x = acc[i][0] + bb[0];
        o.y = acc[i][1] + bb[1];
        o.z = acc[i][2] + bb[2];
        o.w = acc[i][3] + bb[3];
        if (relu) {
            o.x = fmaxf(o.x, 0.0f);
            o.y = fmaxf(o.y, 0.0f);
            o.z = fmaxf(o.z, 0.0f);
            o.w = fmaxf(o.w, 0.0f);
        }
        size_t mrow = (size_t)(m0 + ty * 4 + i);
        if (C) *(float4*)&C[mrow * N + n0 + tx * 4] = o;
        if (Ch) {
            unsigned* cp = Ch + mrow * (N >> 1) + (n0 >> 1) + tx * 2;
            cp[0] = pack2_rne(o.x, o.y);
            cp[1] = pack2_rne(o.z, o.w);
        }
    }
}

// ---- LSTM (unchanged from R15): R13 structure + done-mask skip -------------
__global__ __launch_bounds__(1024) void lstm_kernel(const float* __restrict__ gi,
                                                    const unsigned* __restrict__ wp,
                                                    const int* __restrict__ done,
                                                    const float* __restrict__ h0,
                                                    const float* __restrict__ c0,
                                                    float* __restrict__ out) {
    __shared__ alignas(16) unsigned wo[32768];  // o-rows f16x2: [d4][256][4], 128 KB
    __shared__ alignas(16) unsigned h2u[128];   // h as f16x2, 512 B
    __shared__ float xch[4096];                 // partials [q][gate][u], 16 KB
    int b = blockIdx.x, tt = threadIdx.x;
    int u = tt & 255, q = tt >> 8;
    int q8 = q * 8;

    const uint4* wsrc = (const uint4*)wp;

    // stage o-rows (768..1023) into LDS: wo4[d4*256 + r] = wp4[d4*1024 + 768 + r]
    {
        uint4* dst = (uint4*)wo;
        for (int i4 = tt; i4 < 8192; i4 += 1024) {
            int d4 = i4 >> 8, r = i4 & 255;
            dst[i4] = wsrc[d4 * 1024 + 768 + r];
        }
    }

    // 24 named register weights: k-octets q8..q8+7 of rows u / 256+u / 512+u
    // (compiler remats these into the loop; with the dn-branch they only
    // issue on unmasked steps)
#define LDW(j)                                              \
    uint4 wi##j = wsrc[(q8 + j) * 1024 + u];                \
    uint4 wf##j = wsrc[(q8 + j) * 1024 + 256 + u];          \
    uint4 wg##j = wsrc[(q8 + j) * 1024 + 512 + u];
    LDW(0) LDW(1) LDW(2) LDW(3) LDW(4) LDW(5) LDW(6) LDW(7)
#undef LDW

    // init h (packed f16x2) and per-unit state
    if (tt < 128) {
        h2u[tt] = pack2_rne(h0[b * 256 + 2 * tt], h0[b * 256 + 2 * tt + 1]);
    }
    float c = 0.0f;
    float gv0 = 0.f, gv1 = 0.f, gv2 = 0.f, gv3 = 0.f;
    int dn = done[b];  // ALL threads track dn (block-uniform)
    const float* gbase = gi + (size_t)b * 1024;  // step stride 32*1024 floats
    if (q == 0) {
        c = c0[b * 256 + u];
        gv0 = gbase[u];
        gv1 = gbase[256 + u];
        gv2 = gbase[512 + u];
        gv3 = gbase[768 + u];
    }
    __syncthreads();

    const uint4* h2u4 = (const uint4*)h2u;
    const uint4* wo4 = (const uint4*)wo;

    for (int step = 0; step < 64; ++step) {
        // prefetch next step's done (all threads, uniform) + gate inputs (q==0)
        int dnn = 0;
        if (step < 63) dnn = done[(step + 1) * 32 + b];
        float nx0 = 0.f, nx1 = 0.f, nx2 = 0.f, nx3 = 0.f;
        if (q == 0 && step < 63) {
            const float* gb = gbase + (size_t)(step + 1) * 32768;
            nx0 = gb[u];
            nx1 = gb[256 + u];
            nx2 = gb[512 + u];
            nx3 = gb[768 + u];
        }

        float pI = 0.f, pF = 0.f, pG = 0.f, pO = 0.f;
        if (!dn) {  // m==1: recurrent term live -> do the matvec
#define MV(j) {                                                         \
        uint4 ha = h2u4[q8 + j];      /* broadcast (uniform addr) */    \
        uint4 wv = wo4[(q8 + j) * 256 + u]; /* o row, conflict-free */  \
        pI = dot2(ha.x, wi##j.x, pI); pI = dot2(ha.y, wi##j.y, pI);     \
        pI = dot2(ha.z, wi##j.z, pI); pI = dot2(ha.w, wi##j.w, pI);     \
        pF = dot2(ha.x, wf##j.x, pF); pF = dot2(ha.y, wf##j.y, pF);     \
        pF = dot2(ha.z, wf##j.z, pF); pF = dot2(ha.w, wf##j.w, pF);     \
        pG = dot2(ha.x, wg##j.x, pG); pG = dot2(ha.y, wg##j.y, pG);     \
        pG = dot2(ha.z, wg##j.z, pG); pG = dot2(ha.w, wg##j.w, pG);     \
        pO = dot2(ha.x, wv.x, pO);    pO = dot2(ha.y, wv.y, pO);        \
        pO = dot2(ha.z, wv.z, pO);    pO = dot2(ha.w, wv.w, pO); }
            MV(0) MV(1) MV(2) MV(3) MV(4) MV(5) MV(6) MV(7)
#undef MV
        }

        // post partials: xch[q*1024 + gate*256 + u]
        xch[q * 1024 + u] = pI;
        xch[q * 1024 + 256 + u] = pF;
        xch[q * 1024 + 512 + u] = pG;
        xch[q * 1024 + 768 + u] = pO;
        __syncthreads();  // partials visible; all h2u reads of this step done

        if (q == 0) {
            float m = 1.0f - (float)dn;
            float sI = xch[u] + xch[1024 + u] + xch[2048 + u] + xch[3072 + u];
            float sF = xch[256 + u] + xch[1280 + u] + xch[2304 + u] + xch[3328 + u];
            float sG = xch[512 + u] + xch[1536 + u] + xch[2560 + u] + xch[3584 + u];
            float sO = xch[768 + u] + xch[1792 + u] + xch[2816 + u] + xch[3840 + u];
            float g_i = gv0 + m * sI;
            float g_f = gv1 + m * sF;
            float g_g = gv2 + m * sG;
            float g_o = gv3 + m * sO;
            float si = 1.0f / (1.0f + __expf(-g_i));
            float sf = 1.0f / (1.0f + __expf(-g_f));
            float so = 1.0f / (1.0f + __expf(-g_o));
            float tg = fast_tanh(g_g);
            c = sf * (c * m) + si * tg;
            float hn = so * fast_tanh(c);
            out[((size_t)step * 32 + b) * 256 + u] = hn;
            float hn2 = __shfl_xor(hn, 1);
            if ((u & 1) == 0) {
                unsigned lo = f2h_bits(hn);
                unsigned hi = f2h_bits(hn2);
                h2u[u >> 1] = lo | (hi << 16);
            }
        }
        __syncthreads();  // new h + freed xch visible before next step

        gv0 = nx0; gv1 = nx1; gv2 = nx2; gv3 = nx3;
        dn = dnn;
    }
}

// ---------------------------------------------------------------------------
extern "C" void kernel_launch(void* const* d_in, const int* in_sizes, int n_in,
                              void* d_out, int out_size, void* d_ws, size_t ws_size,
                              hipStream_t stream) {
    const float* x    = (const float*)d_in[0];
    const int*   done = (const int*)d_in[1];
    const float* w1   = (const float*)d_in[2];
    const float* b1   = (const float*)d_in[3];
    const float* w2   = (const float*)d_in[4];
    const float* b2   = (const float*)d_in[5];
    const float* w3   = (const float*)d_in[6];
    const float* b3   = (const float*)d_in[7];
    const float* fcw  = (const float*)d_in[8];
    const float* fcb  = (const float*)d_in[9];
    const float* wih  = (const float*)d_in[10];
    const float* whh  = (const float*)d_in[11];
    const float* bih  = (const float*)d_in[12];
    const float* bhh  = (const float*)d_in[13];
    const float* h0   = (const float*)d_in[14];
    const float* c0   = (const float*)d_in[15];
    float* out = (float*)d_out;
    float* ws = (float*)d_ws;

    // workspace layout (float offsets):
    // z1u (f16): [0, 7,864,320) FLOATS of shorts -- (2048, 32, 15, 16)
    // z2h (uint):[8,000,000, 10,359,296)  -- (2048, 36, 32) pairs
    // z3h (uint):[0, 1,048,576)           (z1u dead after conv2)
    // featsh:    [2,097,152, +524,288) (uint)
    // gi:        [3,145,728, 5,242,880)
    // fcwph:     [10,400,000, +262,144) (uint)
    // wihph:     [10,700,000, +262,144) (uint)
    // w3ph:      [13,000,000, +18,432)  (uint)
    // w1p:       [13,100,000, +4,096)   (uint)
    // w2p:       [13,200,000, +16,384)  (uint)
    // wp (whh packed f16x2, uint[131072]): [13,300,000, 13,431,072)
    //   NOTE: all packed-weight regions live past z1u's end (7,864,320) and
    //   outside z2h -- conv1/conv2 write those after pack_all runs.
    unsigned short* z1u = (unsigned short*)(ws + 0);
    unsigned* z2h = (unsigned*)(ws + 8000000);
    unsigned* z3h = (unsigned*)(ws + 0);
    unsigned* featsh = (unsigned*)(ws + 2097152);
    float* gi     = ws + 3145728;
    unsigned* fcwph = (unsigned*)(ws + 10400000);
    unsigned* wihph = (unsigned*)(ws + 10700000);
    unsigned* w3ph  = (unsigned*)(ws + 13000000);
    unsigned* w1p = (unsigned*)(ws + 13100000);
    unsigned* w2p = (unsigned*)(ws + 13200000);
    unsigned* wp  = (unsigned*)(ws + 13300000);

    // one merged pack kernel: 131072+4096+16384+18432+262144+262144 = 694272
    pack_all_kernel<<<(694272 + 255) / 256, 256, 0, stream>>>(
        whh, w1, w2, w3, fcw, wih, wp, w1p, w2p, w3ph, fcwph, wihph);

    conv1_kernel<<<NIMG, 1024, 0, stream>>>(x, w1p, b1, z1u);
    conv2_kernel<<<NIMG / 2, 768, 0, stream>>>(z1u, w2p, b2, z2h);
    conv3_kernel<<<NIMG / 8, 512, 0, stream>>>(z2h, w3ph, b3, z3h);

    // gemm1: feats = relu(z3 @ fcw^T + fcb), emitted as f16 pairs only
    gemm_bt_h<<<dim3(512 / 64, NIMG / 64), 256, 0, stream>>>(
        z3h, fcwph, fcb, nullptr, nullptr, featsh, NIMG, 512, 512, 1);
    // gemm2: gi = feats @ wih^T + bih + bhh (fp32 out)
    gemm_bt_h<<<dim3(1024 / 64, NIMG / 64), 256, 0, stream>>>(
        featsh, wihph, bih, bhh, gi, nullptr, NIMG, 1024, 256, 0);

    lstm_kernel<<<32, 1024, 0, stream>>>(gi, wp, done, h0, c0, out);
}

// Round 11
// 506.587 us; speedup vs baseline: 1.8119x; 1.0029x over previous
//
#include <hip/hip_runtime.h>
#include <math.h>

// ---------------------------------------------------------------------------
// RecurrentNatureCNN: conv1(8x8,s4) -> conv2(4x4,s2) -> conv3(3x3,s1) -> FC
//                     -> LSTM(T=64,B=32,H=256)
// N = T*B = 2048 images.
// R19: three mechanism-backed fixes on R18:
//  (a) conv1 epilogue was a 2-B scatter (8 shorts @ 480-B stride/thread ->
//      ~2 useful bytes per 64-B line). z1 relaid as [n][gg(4)][pos(225)][4]
//      uints: ONE coalesced uint4 store/thread (lane-consecutive pos ->
//      contiguous). conv2 staging absorbs the transpose (2-B LDS writes,
//      lane-contiguous, conflict-free).
//  (b) gemms run at 1 wave/SIMD (256 blocks = 1/CU): kk-loop ds_read_b128
//      latency fully exposed. Batch kk-reads 4-deep (8 b128 outstanding).
//  (c) lstm masked steps: skip matvec+xch+1 barrier entirely (result is
//      algebraically gv when m=0); q==0 does the degenerate update.
//      Everything else unchanged from R18.
// ---------------------------------------------------------------------------

#define NIMG 2048

typedef _Float16 half2_t __attribute__((ext_vector_type(2)));
typedef __fp16 fp16x2_t __attribute__((ext_vector_type(2)));

__device__ inline unsigned short f2h_bits(float f) {
    union { _Float16 h; unsigned short u; } x;
    x.h = (_Float16)f;
    return x.u;
}

__device__ inline unsigned pack2_rne(float a, float b) {
    return (unsigned)f2h_bits(a) | ((unsigned)f2h_bits(b) << 16);
}

__device__ inline unsigned pack2_fast(float a, float b) {
#if __has_builtin(__builtin_amdgcn_cvt_pkrtz)
    union { fp16x2_t h; unsigned u; } x;
    x.h = __builtin_amdgcn_cvt_pkrtz(a, b);
    return x.u;
#else
    return pack2_rne(a, b);
#endif
}

__device__ inline float dot2(unsigned hu, unsigned wu, float acc) {
    union { unsigned u; half2_t h; } a, b;
    a.u = hu; b.u = wu;
#if __has_builtin(__builtin_amdgcn_fdot2)
    return __builtin_amdgcn_fdot2(a.h, b.h, acc, false);
#else
    return acc + (float)a.h.x * (float)b.h.x + (float)a.h.y * (float)b.h.y;
#endif
}

__device__ inline float fast_tanh(float x) {
    return 1.0f - 2.0f / (__expf(2.0f * x) + 1.0f);
}

// ---- pack_all: every weight prep in ONE kernel -----------------------------
__global__ void pack_all_kernel(const float* __restrict__ whh,
                                const float* __restrict__ w1,
                                const float* __restrict__ w2,
                                const float* __restrict__ w3,
                                const float* __restrict__ fcw,
                                const float* __restrict__ wih,
                                unsigned* __restrict__ wp,
                                unsigned* __restrict__ w1p,
                                unsigned* __restrict__ w2p,
                                unsigned* __restrict__ w3ph,
                                unsigned* __restrict__ fcwph,
                                unsigned* __restrict__ wihph) {
    int idx = blockIdx.x * 256 + threadIdx.x;
    if (idx < 131072) {
        int d4 = idx >> 12, rem = idx & 4095, row = rem >> 2, j = idx & 3;
        const float* s = whh + (size_t)row * 256 + d4 * 8 + j * 2;
        wp[idx] = pack2_rne(s[0], s[1]);
        return;
    }
    idx -= 131072;
    if (idx < 4096) {
        int oc = idx >> 7, rem = idx & 127;
        int ic = rem >> 5, ky = (rem >> 2) & 7, kxp = rem & 3;
        const float* s = w1 + (((size_t)oc * 4 + ic) * 8 + ky) * 8 + kxp * 2;
        w1p[idx] = pack2_rne(s[0], s[1]);
        return;
    }
    idx -= 4096;
    if (idx < 16384) {
        int p = idx >> 6, oc = idx & 63;
        int ic = p >> 3, ky = (p >> 1) & 3, kxp = p & 1;
        const float* s = w2 + (size_t)oc * 512 + ic * 16 + ky * 4 + kxp * 2;
        w2p[idx] = pack2_rne(s[0], s[1]);
        return;
    }
    idx -= 16384;
    if (idx < 18432) {
        int oc = idx & 63, rest = idx >> 6;   // rest = kxy*32 + icp, 0..287
        int icp = rest & 31, kxy = rest >> 5;
        int ky = kxy / 3, kx = kxy - ky * 3;
        const float* s = w3 + (((size_t)oc * 64 + icp * 2) * 3 + ky) * 3 + kx;
        w3ph[idx] = pack2_rne(s[0], s[9]);    // ic stride = 3*3
        return;
    }
    idx -= 18432;
    if (idx < 262144) {
        const float* s = fcw + (size_t)idx * 2;
        fcwph[idx] = pack2_rne(s[0], s[1]);
        return;
    }
    idx -= 262144;
    if (idx < 262144) {
        const float* s = wih + (size_t)idx * 2;
        wihph[idx] = pack2_rne(s[0], s[1]);
    }
}

// ---- conv1: x (n,4,64,64)/255 -> relu -> z1p [n][gg(4)][pos(225)][4] uints -
// R19: epilogue is ONE coalesced uint4 store per thread (oc pairs along x).
__global__ __launch_bounds__(1024) void conv1_kernel(const float* __restrict__ x,
                                                     const unsigned* __restrict__ w1p,
                                                     const float* __restrict__ b,
                                                     unsigned* __restrict__ z1p) {
    __shared__ unsigned short xs[4 * 64 * 64];  // f16, 32768 B
    int n = blockIdx.x;
    int tid = threadIdx.x;
    const float* xp = x + (size_t)n * 16384;
    const float inv = 1.0f / 255.0f;
    for (int i = tid * 4; i < 16384; i += 4096) {
        float4 v = *(const float4*)(xp + i);
        uint2 q;
        q.x = pack2_fast(v.x * inv, v.y * inv);
        q.y = pack2_fast(v.z * inv, v.w * inv);
        *(uint2*)&xs[i] = q;
    }
    __syncthreads();
    int lane = tid & 63, wave = tid >> 6;
    int gg = __builtin_amdgcn_readfirstlane(wave & 3);
    int pos = (wave >> 2) * 64 + lane;  // 0..255
    if (pos < 225) {
        int oy = pos / 15, ox = pos - oy * 15;
        float acc[8];
        const float* bp = b + gg * 8;
#pragma unroll
        for (int u = 0; u < 8; ++u) acc[u] = bp[u];
        for (int ic = 0; ic < 4; ++ic) {
            uint2 qa[8], qb[8];
#pragma unroll
            for (int ky = 0; ky < 8; ++ky) {
                const unsigned short* row = &xs[(ic * 64 + oy * 4 + ky) * 64 + ox * 4];
                qa[ky] = *(const uint2*)row;        // cols +0..3 (2 pairs)
                qb[ky] = *(const uint2*)(row + 4);  // cols +4..7 (2 pairs)
            }
#pragma unroll
            for (int ky = 0; ky < 8; ++ky) {
                const unsigned* wpt = w1p + ((((gg * 8) * 4 + ic) * 8 + ky) * 4);
#pragma unroll
                for (int u = 0; u < 8; ++u) {
                    const unsigned* wu = wpt + u * 128;  // (oc stride 4*8*4)
                    acc[u] = dot2(qa[ky].x, wu[0], acc[u]);
                    acc[u] = dot2(qa[ky].y, wu[1], acc[u]);
                    acc[u] = dot2(qb[ky].x, wu[2], acc[u]);
                    acc[u] = dot2(qb[ky].y, wu[3], acc[u]);
                }
            }
        }
        float r0 = fmaxf(acc[0], 0.f), r1 = fmaxf(acc[1], 0.f);
        float r2 = fmaxf(acc[2], 0.f), r3 = fmaxf(acc[3], 0.f);
        float r4 = fmaxf(acc[4], 0.f), r5 = fmaxf(acc[5], 0.f);
        float r6 = fmaxf(acc[6], 0.f), r7 = fmaxf(acc[7], 0.f);
        uint4 o;
        o.x = pack2_rne(r0, r1);
        o.y = pack2_rne(r2, r3);
        o.z = pack2_rne(r4, r5);
        o.w = pack2_rne(r6, r7);
        *(uint4*)(z1p + (size_t)n * 3600 + gg * 900 + pos * 4) = o;
    }
}

// ---- conv2: z1p -> relu -> z2h f16 [n][pos(36)][ic(64)] --------------------
// R19: staging transposes z1p's [gg][pos][j] into xs [ic][row][col] (2-B LDS
// writes, lane-contiguous cols -> conflict-free).
__global__ __launch_bounds__(768) void conv2_kernel(const unsigned* __restrict__ z1p,
                                                    const unsigned* __restrict__ w2p,
                                                    const float* __restrict__ bias,
                                                    unsigned* __restrict__ z2h) {
    __shared__ unsigned short xs[2][32 * 15 * 16];  // f16, 30720 B
    int tid = threadIdx.x;
    int n0 = blockIdx.x * 2;
    for (int idx = tid; idx < 7200; idx += 768) {
        int img = idx / 3600;
        int r = idx - img * 3600;
        int gg = r / 900;
        int r2 = r - gg * 900;
        int j = r2 / 225;
        int pos = r2 - j * 225;
        unsigned d = z1p[(size_t)(n0 + img) * 3600 + gg * 900 + pos * 4 + j];
        int oc0 = gg * 8 + j * 2;
        int row = pos / 15;
        int col = pos - row * 15;
        xs[img][(oc0 * 15 + row) * 16 + col] = (unsigned short)d;
        xs[img][((oc0 + 1) * 15 + row) * 16 + col] = (unsigned short)(d >> 16);
    }
    __syncthreads();
    int lane = tid & 63, wave = tid >> 6;  // wave 0..11
    int img = wave / 6;
    int oy = wave - img * 6;
    int n = n0 + img;
    float bv = bias[lane];
    float acc[6];
#pragma unroll
    for (int u = 0; u < 6; ++u) acc[u] = bv;
    for (int ic = 0; ic < 32; ++ic) {
        uint4 ra[4], rb[4];
        unsigned wa[4], wb[4];
#pragma unroll
        for (int ky = 0; ky < 4; ++ky) {
            const unsigned short* row = &xs[img][(ic * 15 + oy * 2 + ky) * 16];
            ra[ky] = *(const uint4*)row;        // pairs 0..3  (cols 0..7)
            rb[ky] = *(const uint4*)(row + 8);  // pairs 4..7  (cols 8..15)
            const unsigned* wpp = w2p + ((ic * 4 + ky) * 2) * 64 + lane;
            wa[ky] = wpp[0];   // kx 0,1
            wb[ky] = wpp[64];  // kx 2,3
        }
#pragma unroll
        for (int ky = 0; ky < 4; ++ky) {
            unsigned p[8] = {ra[ky].x, ra[ky].y, ra[ky].z, ra[ky].w,
                             rb[ky].x, rb[ky].y, rb[ky].z, rb[ky].w};
#pragma unroll
            for (int u = 0; u < 6; ++u) {
                acc[u] = dot2(p[u], wa[ky], acc[u]);
                acc[u] = dot2(p[u + 1], wb[ky], acc[u]);
            }
        }
    }
    // epilogue: f16 pairs along ic. z2h[n*1152 + pos*32 + ic/2]
    unsigned* zb = z2h + (size_t)n * 1152;
#pragma unroll
    for (int u = 0; u < 6; ++u) {
        float a = fmaxf(acc[u], 0.0f);
        float a2 = __shfl_xor(a, 1);
        if ((lane & 1) == 0) {
            zb[(oy * 6 + u) * 32 + (lane >> 1)] = pack2_rne(a, a2);
        }
    }
}

// ---- conv3 v2: z2h f16 -> relu -> z3h f16-pairs (n, 512 uints) -------------
__global__ __launch_bounds__(512) void conv3_kernel(const unsigned* __restrict__ z2h,
                                                    const unsigned* __restrict__ w3ph,
                                                    const float* __restrict__ bias,
                                                    unsigned* __restrict__ outp) {
    __shared__ unsigned w3s[18432];    // [kxy(9)][icp(32)][oc(64)], 73728 B
    __shared__ unsigned xs8[8][1152];  // [img][icp(32)][pos(36)], 36864 B
    int tid = threadIdx.x;
    int n0 = blockIdx.x * 8;
    for (int i = tid; i < 18432; i += 512) w3s[i] = w3ph[i];
    for (int i = tid; i < 8 * 1152; i += 512) {
        int img = i / 1152;
        int rem = i - img * 1152;     // src: pos*32 + icp
        int pos = rem >> 5, icp = rem & 31;
        xs8[img][icp * 36 + pos] = z2h[(size_t)(n0 + img) * 1152 + rem];
    }
    __syncthreads();
    int lane = tid & 63, img = tid >> 6;
    int n = n0 + img;
    float bv = bias[lane];
    float acc[4][4];
#pragma unroll
    for (int oy = 0; oy < 4; ++oy)
#pragma unroll
        for (int ox = 0; ox < 4; ++ox) acc[oy][ox] = bv;
    const unsigned* wb = w3s + lane;
    const unsigned* xb = xs8[img];
    for (int icp = 0; icp < 32; ++icp) {
        unsigned xr[36];  // this icp's 6x6 window, uniform-addr broadcast
#pragma unroll
        for (int p4 = 0; p4 < 9; ++p4)
            *(uint4*)&xr[p4 * 4] = *(const uint4*)&xb[icp * 36 + p4 * 4];
        unsigned wv[9];   // batch the 9 weight reads too
#pragma unroll
        for (int k9 = 0; k9 < 9; ++k9)
            wv[k9] = wb[(k9 * 32 + icp) * 64];
#pragma unroll
        for (int ky = 0; ky < 3; ++ky)
#pragma unroll
            for (int kx = 0; kx < 3; ++kx) {
                unsigned w = wv[ky * 3 + kx];
#pragma unroll
                for (int oy = 0; oy < 4; ++oy)
#pragma unroll
                    for (int ox = 0; ox < 4; ++ox)
                        acc[oy][ox] = dot2(xr[(oy + ky) * 6 + ox + kx], w, acc[oy][ox]);
            }
    }
    // z3 feature = oc*16 + oy*4 + ox; pairs along feature dim
    unsigned* op = outp + (size_t)n * 512 + lane * 8;
#pragma unroll
    for (int oy = 0; oy < 4; ++oy) {
        float a0 = fmaxf(acc[oy][0], 0.f), a1 = fmaxf(acc[oy][1], 0.f);
        float a2 = fmaxf(acc[oy][2], 0.f), a3 = fmaxf(acc[oy][3], 0.f);
        op[oy * 2 + 0] = pack2_rne(a0, a1);
        op[oy * 2 + 1] = pack2_rne(a2, a3);
    }
}

// ---- GEMM f16: C(M,N) = [relu]( A @ B^T + bias [+bias2] ), A/B f16 pairs ---
// R19: kk-loop reads batched 4-deep (8 b128 outstanding) -- the gemms run at
// 1 wave/SIMD so nothing else hides the ds_read latency.
__global__ __launch_bounds__(256) void gemm_bt_h(const unsigned* __restrict__ A,
                                                 const unsigned* __restrict__ B,
                                                 const float* __restrict__ bias,
                                                 const float* __restrict__ bias2,
                                                 float* __restrict__ C,
                                                 unsigned* __restrict__ Ch,
                                                 int M, int N, int Kp, int relu) {
    __shared__ unsigned As[16][66];
    __shared__ unsigned Bs[16][66];
    int tid = threadIdx.x;
    int m0 = blockIdx.y * 64, n0 = blockIdx.x * 64;
    int tx = tid & 15, ty = tid >> 4;
    int lr = tid >> 2;
    int lk = (tid & 3) * 4;
    const unsigned* Ap = A + (size_t)(m0 + lr) * Kp + lk;
    const unsigned* Bp = B + (size_t)(n0 + lr) * Kp + lk;
    float acc[4][4];
#pragma unroll
    for (int i = 0; i < 4; ++i)
#pragma unroll
        for (int j = 0; j < 4; ++j) acc[i][j] = 0.0f;

    uint4 av = *(const uint4*)Ap;
    uint4 bv = *(const uint4*)Bp;
    for (int k0 = 0; k0 < Kp; k0 += 16) {
        __syncthreads();
        As[lk + 0][lr] = av.x;
        As[lk + 1][lr] = av.y;
        As[lk + 2][lr] = av.z;
        As[lk + 3][lr] = av.w;
        Bs[lk + 0][lr] = bv.x;
        Bs[lk + 1][lr] = bv.y;
        Bs[lk + 2][lr] = bv.z;
        Bs[lk + 3][lr] = bv.w;
        __syncthreads();
        if (k0 + 16 < Kp) {  // prefetch next tile; hides under compute
            av = *(const uint4*)(Ap + k0 + 16);
            bv = *(const uint4*)(Bp + k0 + 16);
        }
#pragma unroll
        for (int kk = 0; kk < 16; kk += 4) {
            uint4 aF[4], bF[4];
#pragma unroll
            for (int t = 0; t < 4; ++t) {
                aF[t] = *(const uint4*)&As[kk + t][ty * 4];
                bF[t] = *(const uint4*)&Bs[kk + t][tx * 4];
            }
#pragma unroll
            for (int t = 0; t < 4; ++t) {
                unsigned a[4] = {aF[t].x, aF[t].y, aF[t].z, aF[t].w};
                unsigned b[4] = {bF[t].x, bF[t].y, bF[t].z, bF[t].w};
#pragma unroll
                for (int i = 0; i < 4; ++i)
#pragma unroll
                    for (int j = 0; j < 4; ++j)
                        acc[i][j] = dot2(a[i], b[j], acc[i][j]);
            }
        }
    }
    float bb[4];
#pragma unroll
    for (int j = 0; j < 4; ++j) {
        float v = bias[n0 + tx * 4 + j];
        if (bias2) v += bias2[n0 + tx * 4 + j];
        bb[j] = v;
    }
#pragma unroll
    for (int i = 0; i < 4; ++i) {
        float4 o;
        o.x = acc[i][0] + bb[0];
        o.y = acc[i][1] + bb[1];
        o.z = acc[i][2] + bb[2];
        o.w = acc[i][3] + bb[3];
        if (relu) {
            o.x = fmaxf(o.x, 0.0f);
            o.y = fmaxf(o.y, 0.0f);
            o.z = fmaxf(o.z, 0.0f);
            o.w = fmaxf(o.w, 0.0f);
        }
        size_t mrow = (size_t)(m0 + ty * 4 + i);
        if (C) *(float4*)&C[mrow * N + n0 + tx * 4] = o;
        if (Ch) {
            unsigned* cp = Ch + mrow * (N >> 1) + (n0 >> 1) + tx * 2;
            cp[0] = pack2_rne(o.x, o.y);
            cp[1] = pack2_rne(o.z, o.w);
        }
    }
}

// ---- LSTM R19: R15 structure + masked-step fast path -----------------------
__global__ __launch_bounds__(1024) void lstm_kernel(const float* __restrict__ gi,
                                                    const unsigned* __restrict__ wp,
                                                    const int* __restrict__ done,
                                                    const float* __restrict__ h0,
                                                    const float* __restrict__ c0,
                                                    float* __restrict__ out) {
    __shared__ alignas(16) unsigned wo[32768];  // o-rows f16x2: [d4][256][4], 128 KB
    __shared__ alignas(16) unsigned h2u[128];   // h as f16x2, 512 B
    __shared__ float xch[4096];                 // partials [q][gate][u], 16 KB
    int b = blockIdx.x, tt = threadIdx.x;
    int u = tt & 255, q = tt >> 8;
    int q8 = q * 8;

    const uint4* wsrc = (const uint4*)wp;

    // stage o-rows (768..1023) into LDS: wo4[d4*256 + r] = wp4[d4*1024 + 768 + r]
    {
        uint4* dst = (uint4*)wo;
        for (int i4 = tt; i4 < 8192; i4 += 1024) {
            int d4 = i4 >> 8, r = i4 & 255;
            dst[i4] = wsrc[d4 * 1024 + 768 + r];
        }
    }

    // 24 named register weights: k-octets q8..q8+7 of rows u / 256+u / 512+u
    // (compiler remats these into the loop; with the dn-branch they only
    // issue on unmasked steps)
#define LDW(j)                                              \
    uint4 wi##j = wsrc[(q8 + j) * 1024 + u];                \
    uint4 wf##j = wsrc[(q8 + j) * 1024 + 256 + u];          \
    uint4 wg##j = wsrc[(q8 + j) * 1024 + 512 + u];
    LDW(0) LDW(1) LDW(2) LDW(3) LDW(4) LDW(5) LDW(6) LDW(7)
#undef LDW

    // init h (packed f16x2) and per-unit state
    if (tt < 128) {
        h2u[tt] = pack2_rne(h0[b * 256 + 2 * tt], h0[b * 256 + 2 * tt + 1]);
    }
    float c = 0.0f;
    float gv0 = 0.f, gv1 = 0.f, gv2 = 0.f, gv3 = 0.f;
    int dn = done[b];  // ALL threads track dn (block-uniform)
    const float* gbase = gi + (size_t)b * 1024;  // step stride 32*1024 floats
    if (q == 0) {
        c = c0[b * 256 + u];
        gv0 = gbase[u];
        gv1 = gbase[256 + u];
        gv2 = gbase[512 + u];
        gv3 = gbase[768 + u];
    }
    __syncthreads();

    const uint4* h2u4 = (const uint4*)h2u;
    const uint4* wo4 = (const uint4*)wo;

    for (int step = 0; step < 64; ++step) {
        // prefetch next step's done (all threads, uniform) + gate inputs (q==0)
        int dnn = 0;
        if (step < 63) dnn = done[(step + 1) * 32 + b];
        float nx0 = 0.f, nx1 = 0.f, nx2 = 0.f, nx3 = 0.f;
        if (q == 0 && step < 63) {
            const float* gb = gbase + (size_t)(step + 1) * 32768;
            nx0 = gb[u];
            nx1 = gb[256 + u];
            nx2 = gb[512 + u];
            nx3 = gb[768 + u];
        }

        if (!dn) {  // m==1: full matvec + exchange
            float pI = 0.f, pF = 0.f, pG = 0.f, pO = 0.f;
#define MV(j) {                                                         \
        uint4 ha = h2u4[q8 + j];      /* broadcast (uniform addr) */    \
        uint4 wv = wo4[(q8 + j) * 256 + u]; /* o row, conflict-free */  \
        pI = dot2(ha.x, wi##j.x, pI); pI = dot2(ha.y, wi##j.y, pI);     \
        pI = dot2(ha.z, wi##j.z, pI); pI = dot2(ha.w, wi##j.w, pI);     \
        pF = dot2(ha.x, wf##j.x, pF); pF = dot2(ha.y, wf##j.y, pF);     \
        pF = dot2(ha.z, wf##j.z, pF); pF = dot2(ha.w, wf##j.w, pF);     \
        pG = dot2(ha.x, wg##j.x, pG); pG = dot2(ha.y, wg##j.y, pG);     \
        pG = dot2(ha.z, wg##j.z, pG); pG = dot2(ha.w, wg##j.w, pG);     \
        pO = dot2(ha.x, wv.x, pO);    pO = dot2(ha.y, wv.y, pO);        \
        pO = dot2(ha.z, wv.z, pO);    pO = dot2(ha.w, wv.w, pO); }
            MV(0) MV(1) MV(2) MV(3) MV(4) MV(5) MV(6) MV(7)
#undef MV
            xch[q * 1024 + u] = pI;
            xch[q * 1024 + 256 + u] = pF;
            xch[q * 1024 + 512 + u] = pG;
            xch[q * 1024 + 768 + u] = pO;
            __syncthreads();  // partials visible; h2u reads done

            if (q == 0) {
                float sI = xch[u] + xch[1024 + u] + xch[2048 + u] + xch[3072 + u];
                float sF = xch[256 + u] + xch[1280 + u] + xch[2304 + u] + xch[3328 + u];
                float sG = xch[512 + u] + xch[1536 + u] + xch[2560 + u] + xch[3584 + u];
                float sO = xch[768 + u] + xch[1792 + u] + xch[2816 + u] + xch[3840 + u];
                float g_i = gv0 + sI;
                float g_f = gv1 + sF;
                float g_g = gv2 + sG;
                float g_o = gv3 + sO;
                float si = 1.0f / (1.0f + __expf(-g_i));
                float sf = 1.0f / (1.0f + __expf(-g_f));
                float so = 1.0f / (1.0f + __expf(-g_o));
                float tg = fast_tanh(g_g);
                c = sf * c + si * tg;
                float hn = so * fast_tanh(c);
                out[((size_t)step * 32 + b) * 256 + u] = hn;
                float hn2 = __shfl_xor(hn, 1);
                if ((u & 1) == 0) {
                    h2u[u >> 1] = (unsigned)f2h_bits(hn) |
                                  ((unsigned)f2h_bits(hn2) << 16);
                }
            }
            __syncthreads();  // new h visible before next step
        } else {  // m==0: h/c zeroed -> gates = gv; no matvec, no xch, 1 barrier
            if (q == 0) {
                float si = 1.0f / (1.0f + __expf(-gv0));
                float so = 1.0f / (1.0f + __expf(-gv3));
                float tg = fast_tanh(gv2);
                c = si * tg;  // sf*(c*0) + si*tg
                float hn = so * fast_tanh(c);
                out[((size_t)step * 32 + b) * 256 + u] = hn;
                float hn2 = __shfl_xor(hn, 1);
                if ((u & 1) == 0) {
                    h2u[u >> 1] = (unsigned)f2h_bits(hn) |
                                  ((unsigned)f2h_bits(hn2) << 16);
                }
            }
            __syncthreads();  // new h visible before next step
        }

        gv0 = nx0; gv1 = nx1; gv2 = nx2; gv3 = nx3;
        dn = dnn;
    }
}

// ---------------------------------------------------------------------------
extern "C" void kernel_launch(void* const* d_in, const int* in_sizes, int n_in,
                              void* d_out, int out_size, void* d_ws, size_t ws_size,
                              hipStream_t stream) {
    const float* x    = (const float*)d_in[0];
    const int*   done = (const int*)d_in[1];
    const float* w1   = (const float*)d_in[2];
    const float* b1   = (const float*)d_in[3];
    const float* w2   = (const float*)d_in[4];
    const float* b2   = (const float*)d_in[5];
    const float* w3   = (const float*)d_in[6];
    const float* b3   = (const float*)d_in[7];
    const float* fcw  = (const float*)d_in[8];
    const float* fcb  = (const float*)d_in[9];
    const float* wih  = (const float*)d_in[10];
    const float* whh  = (const float*)d_in[11];
    const float* bih  = (const float*)d_in[12];
    const float* bhh  = (const float*)d_in[13];
    const float* h0   = (const float*)d_in[14];
    const float* c0   = (const float*)d_in[15];
    float* out = (float*)d_out;
    float* ws = (float*)d_ws;

    // workspace layout (float offsets):
    // z1p (uint): [0, 7,372,800)  -- (2048, 4, 225, 4)
    // z2h (uint): [8,000,000, 10,359,296)  -- (2048, 36, 32) pairs
    // z3h (uint): [0, 1,048,576)           (z1p dead after conv2)
    // featsh:     [2,097,152, +524,288) (uint)
    // gi:         [3,145,728, 5,242,880)
    // fcwph:      [10,400,000, +262,144) (uint)
    // wihph:      [10,700,000, +262,144) (uint)
    // w3ph:       [13,000,000, +18,432)  (uint)
    // w1p:        [13,100,000, +4,096)   (uint)
    // w2p:        [13,200,000, +16,384)  (uint)
    // wp (whh packed f16x2, uint[131072]): [13,300,000, 13,431,072)
    //   NOTE: all packed-weight regions live past z1p's end and outside z2h
    //   -- conv1/conv2 write those after pack_all runs.
    unsigned* z1p = (unsigned*)(ws + 0);
    unsigned* z2h = (unsigned*)(ws + 8000000);
    unsigned* z3h = (unsigned*)(ws + 0);
    unsigned* featsh = (unsigned*)(ws + 2097152);
    float* gi     = ws + 3145728;
    unsigned* fcwph = (unsigned*)(ws + 10400000);
    unsigned* wihph = (unsigned*)(ws + 10700000);
    unsigned* w3ph  = (unsigned*)(ws + 13000000);
    unsigned* w1p = (unsigned*)(ws + 13100000);
    unsigned* w2p = (unsigned*)(ws + 13200000);
    unsigned* wp  = (unsigned*)(ws + 13300000);

    // one merged pack kernel: 131072+4096+16384+18432+262144+262144 = 694272
    pack_all_kernel<<<(694272 + 255) / 256, 256, 0, stream>>>(
        whh, w1, w2, w3, fcw, wih, wp, w1p, w2p, w3ph, fcwph, wihph);

    conv1_kernel<<<NIMG, 1024, 0, stream>>>(x, w1p, b1, z1p);
    conv2_kernel<<<NIMG / 2, 768, 0, stream>>>(z1p, w2p, b2, z2h);
    conv3_kernel<<<NIMG / 8, 512, 0, stream>>>(z2h, w3ph, b3, z3h);

    // gemm1: feats = relu(z3 @ fcw^T + fcb), emitted as f16 pairs only
    gemm_bt_h<<<dim3(512 / 64, NIMG / 64), 256, 0, stream>>>(
        z3h, fcwph, fcb, nullptr, nullptr, featsh, NIMG, 512, 512, 1);
    // gemm2: gi = feats @ wih^T + bih + bhh (fp32 out)
    gemm_bt_h<<<dim3(1024 / 64, NIMG / 64), 256, 0, stream>>>(
        featsh, wihph, bih, bhh, gi, nullptr, NIMG, 1024, 256, 0);

    lstm_kernel<<<32, 1024, 0, stream>>>(gi, wp, done, h0, c0, out);
}

// Round 12
// 506.448 us; speedup vs baseline: 1.8124x; 1.0003x over previous
//
#include <hip/hip_runtime.h>
#include <math.h>

// ---------------------------------------------------------------------------
// RecurrentNatureCNN: conv1(8x8,s4) -> conv2(4x4,s2) -> conv3(3x3,s1) -> FC
//                     -> LSTM(T=64,B=32,H=256)
// N = T*B = 2048 images.
// R20: ONE change vs R19: lstm __launch_bounds__(1024, 1).
//      Mechanism: lstm's 147 KB LDS hard-caps it at 1 block/CU = 4 waves/
//      SIMD, so any VGPR count <=128 costs ZERO occupancy; and a 1024-thread
//      block hard-caps VGPR at 128 (16 waves must co-reside), so the budget
//      cannot over-shoot. R13-R19 the compiler targeted 8 waves/SIMD (64
//      VGPR) and rematerialized the 96 weight dwords into the step loop ->
//      384 B/thread L2 stream per unmasked step = the 6.2K cyc/step floor.
//      launch_bounds(1024,1) = "1 wave/EU (or 1 block/CU) is enough" ->
//      128-VGPR budget -> weights can stay register-resident.
//      Confirmation: VGPR_Count 64 -> ~110-128, lstm 117 -> ~70-95 us.
//      Spill signature (revert if seen): WRITE_SIZE >> 6 MB.
//      Everything else byte-identical to R19.
// ---------------------------------------------------------------------------

#define NIMG 2048

typedef _Float16 half2_t __attribute__((ext_vector_type(2)));
typedef __fp16 fp16x2_t __attribute__((ext_vector_type(2)));

__device__ inline unsigned short f2h_bits(float f) {
    union { _Float16 h; unsigned short u; } x;
    x.h = (_Float16)f;
    return x.u;
}

__device__ inline unsigned pack2_rne(float a, float b) {
    return (unsigned)f2h_bits(a) | ((unsigned)f2h_bits(b) << 16);
}

__device__ inline unsigned pack2_fast(float a, float b) {
#if __has_builtin(__builtin_amdgcn_cvt_pkrtz)
    union { fp16x2_t h; unsigned u; } x;
    x.h = __builtin_amdgcn_cvt_pkrtz(a, b);
    return x.u;
#else
    return pack2_rne(a, b);
#endif
}

__device__ inline float dot2(unsigned hu, unsigned wu, float acc) {
    union { unsigned u; half2_t h; } a, b;
    a.u = hu; b.u = wu;
#if __has_builtin(__builtin_amdgcn_fdot2)
    return __builtin_amdgcn_fdot2(a.h, b.h, acc, false);
#else
    return acc + (float)a.h.x * (float)b.h.x + (float)a.h.y * (float)b.h.y;
#endif
}

__device__ inline float fast_tanh(float x) {
    return 1.0f - 2.0f / (__expf(2.0f * x) + 1.0f);
}

// ---- pack_all: every weight prep in ONE kernel -----------------------------
__global__ void pack_all_kernel(const float* __restrict__ whh,
                                const float* __restrict__ w1,
                                const float* __restrict__ w2,
                                const float* __restrict__ w3,
                                const float* __restrict__ fcw,
                                const float* __restrict__ wih,
                                unsigned* __restrict__ wp,
                                unsigned* __restrict__ w1p,
                                unsigned* __restrict__ w2p,
                                unsigned* __restrict__ w3ph,
                                unsigned* __restrict__ fcwph,
                                unsigned* __restrict__ wihph) {
    int idx = blockIdx.x * 256 + threadIdx.x;
    if (idx < 131072) {
        int d4 = idx >> 12, rem = idx & 4095, row = rem >> 2, j = idx & 3;
        const float* s = whh + (size_t)row * 256 + d4 * 8 + j * 2;
        wp[idx] = pack2_rne(s[0], s[1]);
        return;
    }
    idx -= 131072;
    if (idx < 4096) {
        int oc = idx >> 7, rem = idx & 127;
        int ic = rem >> 5, ky = (rem >> 2) & 7, kxp = rem & 3;
        const float* s = w1 + (((size_t)oc * 4 + ic) * 8 + ky) * 8 + kxp * 2;
        w1p[idx] = pack2_rne(s[0], s[1]);
        return;
    }
    idx -= 4096;
    if (idx < 16384) {
        int p = idx >> 6, oc = idx & 63;
        int ic = p >> 3, ky = (p >> 1) & 3, kxp = p & 1;
        const float* s = w2 + (size_t)oc * 512 + ic * 16 + ky * 4 + kxp * 2;
        w2p[idx] = pack2_rne(s[0], s[1]);
        return;
    }
    idx -= 16384;
    if (idx < 18432) {
        int oc = idx & 63, rest = idx >> 6;   // rest = kxy*32 + icp, 0..287
        int icp = rest & 31, kxy = rest >> 5;
        int ky = kxy / 3, kx = kxy - ky * 3;
        const float* s = w3 + (((size_t)oc * 64 + icp * 2) * 3 + ky) * 3 + kx;
        w3ph[idx] = pack2_rne(s[0], s[9]);    // ic stride = 3*3
        return;
    }
    idx -= 18432;
    if (idx < 262144) {
        const float* s = fcw + (size_t)idx * 2;
        fcwph[idx] = pack2_rne(s[0], s[1]);
        return;
    }
    idx -= 262144;
    if (idx < 262144) {
        const float* s = wih + (size_t)idx * 2;
        wihph[idx] = pack2_rne(s[0], s[1]);
    }
}

// ---- conv1: x (n,4,64,64)/255 -> relu -> z1p [n][gg(4)][pos(225)][4] uints -
__global__ __launch_bounds__(1024) void conv1_kernel(const float* __restrict__ x,
                                                     const unsigned* __restrict__ w1p,
                                                     const float* __restrict__ b,
                                                     unsigned* __restrict__ z1p) {
    __shared__ unsigned short xs[4 * 64 * 64];  // f16, 32768 B
    int n = blockIdx.x;
    int tid = threadIdx.x;
    const float* xp = x + (size_t)n * 16384;
    const float inv = 1.0f / 255.0f;
    for (int i = tid * 4; i < 16384; i += 4096) {
        float4 v = *(const float4*)(xp + i);
        uint2 q;
        q.x = pack2_fast(v.x * inv, v.y * inv);
        q.y = pack2_fast(v.z * inv, v.w * inv);
        *(uint2*)&xs[i] = q;
    }
    __syncthreads();
    int lane = tid & 63, wave = tid >> 6;
    int gg = __builtin_amdgcn_readfirstlane(wave & 3);
    int pos = (wave >> 2) * 64 + lane;  // 0..255
    if (pos < 225) {
        int oy = pos / 15, ox = pos - oy * 15;
        float acc[8];
        const float* bp = b + gg * 8;
#pragma unroll
        for (int u = 0; u < 8; ++u) acc[u] = bp[u];
        for (int ic = 0; ic < 4; ++ic) {
            uint2 qa[8], qb[8];
#pragma unroll
            for (int ky = 0; ky < 8; ++ky) {
                const unsigned short* row = &xs[(ic * 64 + oy * 4 + ky) * 64 + ox * 4];
                qa[ky] = *(const uint2*)row;        // cols +0..3 (2 pairs)
                qb[ky] = *(const uint2*)(row + 4);  // cols +4..7 (2 pairs)
            }
#pragma unroll
            for (int ky = 0; ky < 8; ++ky) {
                const unsigned* wpt = w1p + ((((gg * 8) * 4 + ic) * 8 + ky) * 4);
#pragma unroll
                for (int u = 0; u < 8; ++u) {
                    const unsigned* wu = wpt + u * 128;  // (oc stride 4*8*4)
                    acc[u] = dot2(qa[ky].x, wu[0], acc[u]);
                    acc[u] = dot2(qa[ky].y, wu[1], acc[u]);
                    acc[u] = dot2(qb[ky].x, wu[2], acc[u]);
                    acc[u] = dot2(qb[ky].y, wu[3], acc[u]);
                }
            }
        }
        float r0 = fmaxf(acc[0], 0.f), r1 = fmaxf(acc[1], 0.f);
        float r2 = fmaxf(acc[2], 0.f), r3 = fmaxf(acc[3], 0.f);
        float r4 = fmaxf(acc[4], 0.f), r5 = fmaxf(acc[5], 0.f);
        float r6 = fmaxf(acc[6], 0.f), r7 = fmaxf(acc[7], 0.f);
        uint4 o;
        o.x = pack2_rne(r0, r1);
        o.y = pack2_rne(r2, r3);
        o.z = pack2_rne(r4, r5);
        o.w = pack2_rne(r6, r7);
        *(uint4*)(z1p + (size_t)n * 3600 + gg * 900 + pos * 4) = o;
    }
}

// ---- conv2: z1p -> relu -> z2h f16 [n][pos(36)][ic(64)] --------------------
__global__ __launch_bounds__(768) void conv2_kernel(const unsigned* __restrict__ z1p,
                                                    const unsigned* __restrict__ w2p,
                                                    const float* __restrict__ bias,
                                                    unsigned* __restrict__ z2h) {
    __shared__ unsigned short xs[2][32 * 15 * 16];  // f16, 30720 B
    int tid = threadIdx.x;
    int n0 = blockIdx.x * 2;
    for (int idx = tid; idx < 7200; idx += 768) {
        int img = idx / 3600;
        int r = idx - img * 3600;
        int gg = r / 900;
        int r2 = r - gg * 900;
        int j = r2 / 225;
        int pos = r2 - j * 225;
        unsigned d = z1p[(size_t)(n0 + img) * 3600 + gg * 900 + pos * 4 + j];
        int oc0 = gg * 8 + j * 2;
        int row = pos / 15;
        int col = pos - row * 15;
        xs[img][(oc0 * 15 + row) * 16 + col] = (unsigned short)d;
        xs[img][((oc0 + 1) * 15 + row) * 16 + col] = (unsigned short)(d >> 16);
    }
    __syncthreads();
    int lane = tid & 63, wave = tid >> 6;  // wave 0..11
    int img = wave / 6;
    int oy = wave - img * 6;
    int n = n0 + img;
    float bv = bias[lane];
    float acc[6];
#pragma unroll
    for (int u = 0; u < 6; ++u) acc[u] = bv;
    for (int ic = 0; ic < 32; ++ic) {
        uint4 ra[4], rb[4];
        unsigned wa[4], wb[4];
#pragma unroll
        for (int ky = 0; ky < 4; ++ky) {
            const unsigned short* row = &xs[img][(ic * 15 + oy * 2 + ky) * 16];
            ra[ky] = *(const uint4*)row;        // pairs 0..3  (cols 0..7)
            rb[ky] = *(const uint4*)(row + 8);  // pairs 4..7  (cols 8..15)
            const unsigned* wpp = w2p + ((ic * 4 + ky) * 2) * 64 + lane;
            wa[ky] = wpp[0];   // kx 0,1
            wb[ky] = wpp[64];  // kx 2,3
        }
#pragma unroll
        for (int ky = 0; ky < 4; ++ky) {
            unsigned p[8] = {ra[ky].x, ra[ky].y, ra[ky].z, ra[ky].w,
                             rb[ky].x, rb[ky].y, rb[ky].z, rb[ky].w};
#pragma unroll
            for (int u = 0; u < 6; ++u) {
                acc[u] = dot2(p[u], wa[ky], acc[u]);
                acc[u] = dot2(p[u + 1], wb[ky], acc[u]);
            }
        }
    }
    // epilogue: f16 pairs along ic. z2h[n*1152 + pos*32 + ic/2]
    unsigned* zb = z2h + (size_t)n * 1152;
#pragma unroll
    for (int u = 0; u < 6; ++u) {
        float a = fmaxf(acc[u], 0.0f);
        float a2 = __shfl_xor(a, 1);
        if ((lane & 1) == 0) {
            zb[(oy * 6 + u) * 32 + (lane >> 1)] = pack2_rne(a, a2);
        }
    }
}

// ---- conv3 v2: z2h f16 -> relu -> z3h f16-pairs (n, 512 uints) -------------
__global__ __launch_bounds__(512) void conv3_kernel(const unsigned* __restrict__ z2h,
                                                    const unsigned* __restrict__ w3ph,
                                                    const float* __restrict__ bias,
                                                    unsigned* __restrict__ outp) {
    __shared__ unsigned w3s[18432];    // [kxy(9)][icp(32)][oc(64)], 73728 B
    __shared__ unsigned xs8[8][1152];  // [img][icp(32)][pos(36)], 36864 B
    int tid = threadIdx.x;
    int n0 = blockIdx.x * 8;
    for (int i = tid; i < 18432; i += 512) w3s[i] = w3ph[i];
    for (int i = tid; i < 8 * 1152; i += 512) {
        int img = i / 1152;
        int rem = i - img * 1152;     // src: pos*32 + icp
        int pos = rem >> 5, icp = rem & 31;
        xs8[img][icp * 36 + pos] = z2h[(size_t)(n0 + img) * 1152 + rem];
    }
    __syncthreads();
    int lane = tid & 63, img = tid >> 6;
    int n = n0 + img;
    float bv = bias[lane];
    float acc[4][4];
#pragma unroll
    for (int oy = 0; oy < 4; ++oy)
#pragma unroll
        for (int ox = 0; ox < 4; ++ox) acc[oy][ox] = bv;
    const unsigned* wb = w3s + lane;
    const unsigned* xb = xs8[img];
    for (int icp = 0; icp < 32; ++icp) {
        unsigned xr[36];  // this icp's 6x6 window, uniform-addr broadcast
#pragma unroll
        for (int p4 = 0; p4 < 9; ++p4)
            *(uint4*)&xr[p4 * 4] = *(const uint4*)&xb[icp * 36 + p4 * 4];
        unsigned wv[9];   // batch the 9 weight reads too
#pragma unroll
        for (int k9 = 0; k9 < 9; ++k9)
            wv[k9] = wb[(k9 * 32 + icp) * 64];
#pragma unroll
        for (int ky = 0; ky < 3; ++ky)
#pragma unroll
            for (int kx = 0; kx < 3; ++kx) {
                unsigned w = wv[ky * 3 + kx];
#pragma unroll
                for (int oy = 0; oy < 4; ++oy)
#pragma unroll
                    for (int ox = 0; ox < 4; ++ox)
                        acc[oy][ox] = dot2(xr[(oy + ky) * 6 + ox + kx], w, acc[oy][ox]);
            }
    }
    // z3 feature = oc*16 + oy*4 + ox; pairs along feature dim
    unsigned* op = outp + (size_t)n * 512 + lane * 8;
#pragma unroll
    for (int oy = 0; oy < 4; ++oy) {
        float a0 = fmaxf(acc[oy][0], 0.f), a1 = fmaxf(acc[oy][1], 0.f);
        float a2 = fmaxf(acc[oy][2], 0.f), a3 = fmaxf(acc[oy][3], 0.f);
        op[oy * 2 + 0] = pack2_rne(a0, a1);
        op[oy * 2 + 1] = pack2_rne(a2, a3);
    }
}

// ---- GEMM f16: C(M,N) = [relu]( A @ B^T + bias [+bias2] ), A/B f16 pairs ---
__global__ __launch_bounds__(256) void gemm_bt_h(const unsigned* __restrict__ A,
                                                 const unsigned* __restrict__ B,
                                                 const float* __restrict__ bias,
                                                 const float* __restrict__ bias2,
                                                 float* __restrict__ C,
                                                 unsigned* __restrict__ Ch,
                                                 int M, int N, int Kp, int relu) {
    __shared__ unsigned As[16][66];
    __shared__ unsigned Bs[16][66];
    int tid = threadIdx.x;
    int m0 = blockIdx.y * 64, n0 = blockIdx.x * 64;
    int tx = tid & 15, ty = tid >> 4;
    int lr = tid >> 2;
    int lk = (tid & 3) * 4;
    const unsigned* Ap = A + (size_t)(m0 + lr) * Kp + lk;
    const unsigned* Bp = B + (size_t)(n0 + lr) * Kp + lk;
    float acc[4][4];
#pragma unroll
    for (int i = 0; i < 4; ++i)
#pragma unroll
        for (int j = 0; j < 4; ++j) acc[i][j] = 0.0f;

    uint4 av = *(const uint4*)Ap;
    uint4 bv = *(const uint4*)Bp;
    for (int k0 = 0; k0 < Kp; k0 += 16) {
        __syncthreads();
        As[lk + 0][lr] = av.x;
        As[lk + 1][lr] = av.y;
        As[lk + 2][lr] = av.z;
        As[lk + 3][lr] = av.w;
        Bs[lk + 0][lr] = bv.x;
        Bs[lk + 1][lr] = bv.y;
        Bs[lk + 2][lr] = bv.z;
        Bs[lk + 3][lr] = bv.w;
        __syncthreads();
        if (k0 + 16 < Kp) {  // prefetch next tile; hides under compute
            av = *(const uint4*)(Ap + k0 + 16);
            bv = *(const uint4*)(Bp + k0 + 16);
        }
#pragma unroll
        for (int kk = 0; kk < 16; kk += 4) {
            uint4 aF[4], bF[4];
#pragma unroll
            for (int t = 0; t < 4; ++t) {
                aF[t] = *(const uint4*)&As[kk + t][ty * 4];
                bF[t] = *(const uint4*)&Bs[kk + t][tx * 4];
            }
#pragma unroll
            for (int t = 0; t < 4; ++t) {
                unsigned a[4] = {aF[t].x, aF[t].y, aF[t].z, aF[t].w};
                unsigned b[4] = {bF[t].x, bF[t].y, bF[t].z, bF[t].w};
#pragma unroll
                for (int i = 0; i < 4; ++i)
#pragma unroll
                    for (int j = 0; j < 4; ++j)
                        acc[i][j] = dot2(a[i], b[j], acc[i][j]);
            }
        }
    }
    float bb[4];
#pragma unroll
    for (int j = 0; j < 4; ++j) {
        float v = bias[n0 + tx * 4 + j];
        if (bias2) v += bias2[n0 + tx * 4 + j];
        bb[j] = v;
    }
#pragma unroll
    for (int i = 0; i < 4; ++i) {
        float4 o;
        o.x = acc[i][0] + bb[0];
        o.y = acc[i][1] + bb[1];
        o.z = acc[i][2] + bb[2];
        o.w = acc[i][3] + bb[3];
        if (relu) {
            o.x = fmaxf(o.x, 0.0f);
            o.y = fmaxf(o.y, 0.0f);
            o.z = fmaxf(o.z, 0.0f);
            o.w = fmaxf(o.w, 0.0f);
        }
        size_t mrow = (size_t)(m0 + ty * 4 + i);
        if (C) *(float4*)&C[mrow * N + n0 + tx * 4] = o;
        if (Ch) {
            unsigned* cp = Ch + mrow * (N >> 1) + (n0 >> 1) + tx * 2;
            cp[0] = pack2_rne(o.x, o.y);
            cp[1] = pack2_rne(o.z, o.w);
        }
    }
}

// ---- LSTM R20: = R19 + __launch_bounds__(1024, 1) --------------------------
// 147 KB LDS caps at 1 block/CU (4 waves/SIMD); 1024-thr block caps VGPR at
// 128. Budget 64 -> 128 costs zero occupancy and lets the 96 weight dwords
// stay register-resident instead of re-streaming from L2 every unmasked step.
__global__ __launch_bounds__(1024, 1) void lstm_kernel(const float* __restrict__ gi,
                                                       const unsigned* __restrict__ wp,
                                                       const int* __restrict__ done,
                                                       const float* __restrict__ h0,
                                                       const float* __restrict__ c0,
                                                       float* __restrict__ out) {
    __shared__ alignas(16) unsigned wo[32768];  // o-rows f16x2: [d4][256][4], 128 KB
    __shared__ alignas(16) unsigned h2u[128];   // h as f16x2, 512 B
    __shared__ float xch[4096];                 // partials [q][gate][u], 16 KB
    int b = blockIdx.x, tt = threadIdx.x;
    int u = tt & 255, q = tt >> 8;
    int q8 = q * 8;

    const uint4* wsrc = (const uint4*)wp;

    // stage o-rows (768..1023) into LDS: wo4[d4*256 + r] = wp4[d4*1024 + 768 + r]
    {
        uint4* dst = (uint4*)wo;
        for (int i4 = tt; i4 < 8192; i4 += 1024) {
            int d4 = i4 >> 8, r = i4 & 255;
            dst[i4] = wsrc[d4 * 1024 + 768 + r];
        }
    }

    // 24 named register weights: k-octets q8..q8+7 of rows u / 256+u / 512+u
#define LDW(j)                                              \
    uint4 wi##j = wsrc[(q8 + j) * 1024 + u];                \
    uint4 wf##j = wsrc[(q8 + j) * 1024 + 256 + u];          \
    uint4 wg##j = wsrc[(q8 + j) * 1024 + 512 + u];
    LDW(0) LDW(1) LDW(2) LDW(3) LDW(4) LDW(5) LDW(6) LDW(7)
#undef LDW

    // init h (packed f16x2) and per-unit state
    if (tt < 128) {
        h2u[tt] = pack2_rne(h0[b * 256 + 2 * tt], h0[b * 256 + 2 * tt + 1]);
    }
    float c = 0.0f;
    float gv0 = 0.f, gv1 = 0.f, gv2 = 0.f, gv3 = 0.f;
    int dn = done[b];  // ALL threads track dn (block-uniform)
    const float* gbase = gi + (size_t)b * 1024;  // step stride 32*1024 floats
    if (q == 0) {
        c = c0[b * 256 + u];
        gv0 = gbase[u];
        gv1 = gbase[256 + u];
        gv2 = gbase[512 + u];
        gv3 = gbase[768 + u];
    }
    __syncthreads();

    const uint4* h2u4 = (const uint4*)h2u;
    const uint4* wo4 = (const uint4*)wo;

    for (int step = 0; step < 64; ++step) {
        // prefetch next step's done (all threads, uniform) + gate inputs (q==0)
        int dnn = 0;
        if (step < 63) dnn = done[(step + 1) * 32 + b];
        float nx0 = 0.f, nx1 = 0.f, nx2 = 0.f, nx3 = 0.f;
        if (q == 0 && step < 63) {
            const float* gb = gbase + (size_t)(step + 1) * 32768;
            nx0 = gb[u];
            nx1 = gb[256 + u];
            nx2 = gb[512 + u];
            nx3 = gb[768 + u];
        }

        if (!dn) {  // m==1: full matvec + exchange
            float pI = 0.f, pF = 0.f, pG = 0.f, pO = 0.f;
#define MV(j) {                                                         \
        uint4 ha = h2u4[q8 + j];      /* broadcast (uniform addr) */    \
        uint4 wv = wo4[(q8 + j) * 256 + u]; /* o row, conflict-free */  \
        pI = dot2(ha.x, wi##j.x, pI); pI = dot2(ha.y, wi##j.y, pI);     \
        pI = dot2(ha.z, wi##j.z, pI); pI = dot2(ha.w, wi##j.w, pI);     \
        pF = dot2(ha.x, wf##j.x, pF); pF = dot2(ha.y, wf##j.y, pF);     \
        pF = dot2(ha.z, wf##j.z, pF); pF = dot2(ha.w, wf##j.w, pF);     \
        pG = dot2(ha.x, wg##j.x, pG); pG = dot2(ha.y, wg##j.y, pG);     \
        pG = dot2(ha.z, wg##j.z, pG); pG = dot2(ha.w, wg##j.w, pG);     \
        pO = dot2(ha.x, wv.x, pO);    pO = dot2(ha.y, wv.y, pO);        \
        pO = dot2(ha.z, wv.z, pO);    pO = dot2(ha.w, wv.w, pO); }
            MV(0) MV(1) MV(2) MV(3) MV(4) MV(5) MV(6) MV(7)
#undef MV
            xch[q * 1024 + u] = pI;
            xch[q * 1024 + 256 + u] = pF;
            xch[q * 1024 + 512 + u] = pG;
            xch[q * 1024 + 768 + u] = pO;
            __syncthreads();  // partials visible; h2u reads done

            if (q == 0) {
                float sI = xch[u] + xch[1024 + u] + xch[2048 + u] + xch[3072 + u];
                float sF = xch[256 + u] + xch[1280 + u] + xch[2304 + u] + xch[3328 + u];
                float sG = xch[512 + u] + xch[1536 + u] + xch[2560 + u] + xch[3584 + u];
                float sO = xch[768 + u] + xch[1792 + u] + xch[2816 + u] + xch[3840 + u];
                float g_i = gv0 + sI;
                float g_f = gv1 + sF;
                float g_g = gv2 + sG;
                float g_o = gv3 + sO;
                float si = 1.0f / (1.0f + __expf(-g_i));
                float sf = 1.0f / (1.0f + __expf(-g_f));
                float so = 1.0f / (1.0f + __expf(-g_o));
                float tg = fast_tanh(g_g);
                c = sf * c + si * tg;
                float hn = so * fast_tanh(c);
                out[((size_t)step * 32 + b) * 256 + u] = hn;
                float hn2 = __shfl_xor(hn, 1);
                if ((u & 1) == 0) {
                    h2u[u >> 1] = (unsigned)f2h_bits(hn) |
                                  ((unsigned)f2h_bits(hn2) << 16);
                }
            }
            __syncthreads();  // new h visible before next step
        } else {  // m==0: h/c zeroed -> gates = gv; no matvec, no xch, 1 barrier
            if (q == 0) {
                float si = 1.0f / (1.0f + __expf(-gv0));
                float so = 1.0f / (1.0f + __expf(-gv3));
                float tg = fast_tanh(gv2);
                c = si * tg;  // sf*(c*0) + si*tg
                float hn = so * fast_tanh(c);
                out[((size_t)step * 32 + b) * 256 + u] = hn;
                float hn2 = __shfl_xor(hn, 1);
                if ((u & 1) == 0) {
                    h2u[u >> 1] = (unsigned)f2h_bits(hn) |
                                  ((unsigned)f2h_bits(hn2) << 16);
                }
            }
            __syncthreads();  // new h visible before next step
        }

        gv0 = nx0; gv1 = nx1; gv2 = nx2; gv3 = nx3;
        dn = dnn;
    }
}

// ---------------------------------------------------------------------------
extern "C" void kernel_launch(void* const* d_in, const int* in_sizes, int n_in,
                              void* d_out, int out_size, void* d_ws, size_t ws_size,
                              hipStream_t stream) {
    const float* x    = (const float*)d_in[0];
    const int*   done = (const int*)d_in[1];
    const float* w1   = (const float*)d_in[2];
    const float* b1   = (const float*)d_in[3];
    const float* w2   = (const float*)d_in[4];
    const float* b2   = (const float*)d_in[5];
    const float* w3   = (const float*)d_in[6];
    const float* b3   = (const float*)d_in[7];
    const float* fcw  = (const float*)d_in[8];
    const float* fcb  = (const float*)d_in[9];
    const float* wih  = (const float*)d_in[10];
    const float* whh  = (const float*)d_in[11];
    const float* bih  = (const float*)d_in[12];
    const float* bhh  = (const float*)d_in[13];
    const float* h0   = (const float*)d_in[14];
    const float* c0   = (const float*)d_in[15];
    float* out = (float*)d_out;
    float* ws = (float*)d_ws;

    // workspace layout (float offsets):
    // z1p (uint): [0, 7,372,800)  -- (2048, 4, 225, 4)
    // z2h (uint): [8,000,000, 10,359,296)  -- (2048, 36, 32) pairs
    // z3h (uint): [0, 1,048,576)           (z1p dead after conv2)
    // featsh:     [2,097,152, +524,288) (uint)
    // gi:         [3,145,728, 5,242,880)
    // fcwph:      [10,400,000, +262,144) (uint)
    // wihph:      [10,700,000, +262,144) (uint)
    // w3ph:       [13,000,000, +18,432)  (uint)
    // w1p:        [13,100,000, +4,096)   (uint)
    // w2p:        [13,200,000, +16,384)  (uint)
    // wp (whh packed f16x2, uint[131072]): [13,300,000, 13,431,072)
    //   NOTE: all packed-weight regions live past z1p's end and outside z2h
    //   -- conv1/conv2 write those after pack_all runs.
    unsigned* z1p = (unsigned*)(ws + 0);
    unsigned* z2h = (unsigned*)(ws + 8000000);
    unsigned* z3h = (unsigned*)(ws + 0);
    unsigned* featsh = (unsigned*)(ws + 2097152);
    float* gi     = ws + 3145728;
    unsigned* fcwph = (unsigned*)(ws + 10400000);
    unsigned* wihph = (unsigned*)(ws + 10700000);
    unsigned* w3ph  = (unsigned*)(ws + 13000000);
    unsigned* w1p = (unsigned*)(ws + 13100000);
    unsigned* w2p = (unsigned*)(ws + 13200000);
    unsigned* wp  = (unsigned*)(ws + 13300000);

    // one merged pack kernel: 131072+4096+16384+18432+262144+262144 = 694272
    pack_all_kernel<<<(694272 + 255) / 256, 256, 0, stream>>>(
        whh, w1, w2, w3, fcw, wih, wp, w1p, w2p, w3ph, fcwph, wihph);

    conv1_kernel<<<NIMG, 1024, 0, stream>>>(x, w1p, b1, z1p);
    conv2_kernel<<<NIMG / 2, 768, 0, stream>>>(z1p, w2p, b2, z2h);
    conv3_kernel<<<NIMG / 8, 512, 0, stream>>>(z2h, w3ph, b3, z3h);

    // gemm1: feats = relu(z3 @ fcw^T + fcb), emitted as f16 pairs only
    gemm_bt_h<<<dim3(512 / 64, NIMG / 64), 256, 0, stream>>>(
        z3h, fcwph, fcb, nullptr, nullptr, featsh, NIMG, 512, 512, 1);
    // gemm2: gi = feats @ wih^T + bih + bhh (fp32 out)
    gemm_bt_h<<<dim3(1024 / 64, NIMG / 64), 256, 0, stream>>>(
        featsh, wihph, bih, bhh, gi, nullptr, NIMG, 1024, 256, 0);

    lstm_kernel<<<32, 1024, 0, stream>>>(gi, wp, done, h0, c0, out);
}